// Round 6
// baseline (1147.979 us; speedup 1.0000x reference)
//
#include <hip/hip_runtime.h>
#include <stdint.h>

typedef unsigned short u16;
typedef unsigned int u32;
typedef __attribute__((ext_vector_type(8))) short short8;   // 8 x bf16 (4 VGPRs)
typedef __attribute__((ext_vector_type(4))) float f32x4;

#define DEVI static __device__ __forceinline__

#define S_LEN 2048
#define DMODEL 1024
#define NHEAD 16
#define DK 64
#define NEG_INF (-__builtin_inff())
// u = bitcast((bits>>9)|0x3f800000)-1; boundary 0.9f = 7549747/2^23
// keep:   u > 0.9  <=> bits >= 7549748*512
// dropout keep: u < 0.9  <=> bits <  7549747*512
#define KEEPC 3865470976u
#define DROPC 3865470464u

DEVI u16 f2bf(float f) {
  u32 u = __builtin_bit_cast(u32, f);
  u32 r = u + 0x7fffu + ((u >> 16) & 1u);   // RNE
  return (u16)(r >> 16);
}

DEVI short8 cvt8(float4 a, float4 b) {
  short8 r;
  r[0] = (short)f2bf(a.x); r[1] = (short)f2bf(a.y);
  r[2] = (short)f2bf(a.z); r[3] = (short)f2bf(a.w);
  r[4] = (short)f2bf(b.x); r[5] = (short)f2bf(b.y);
  r[6] = (short)f2bf(b.z); r[7] = (short)f2bf(b.w);
  return r;
}

// JAX threefry2x32 (20 rounds), partitionable draw (default since jax 0.4.36):
// key (0,key), ctr (0,i), bits = o0 ^ o1. key is compile-time const at call
// sites -> K2 and injections fold. Validated bit-exact in rounds 2/3.
DEVI u32 tf_bits(u32 key, u32 i) {
  const u32 K2 = key ^ 0x1BD11BDAu;
  u32 x0 = 0u, x1 = i + key;
#define TFR(r) { x0 += x1; x1 = __builtin_rotateleft32(x1, r); x1 ^= x0; }
  TFR(13) TFR(15) TFR(26) TFR(6)  x0 += key; x1 += K2 + 1u;
  TFR(17) TFR(29) TFR(16) TFR(24) x0 += K2;  x1 += 2u;
  TFR(13) TFR(15) TFR(26) TFR(6)  /*x0+=0*/  x1 += key + 3u;
  TFR(17) TFR(29) TFR(16) TFR(24) x0 += key; x1 += K2 + 4u;
  TFR(13) TFR(15) TFR(26) TFR(6)  x0 += K2;  x1 += 5u;
#undef TFR
  return x0 ^ x1;
}

// 16 keep draws for one 16q x 64k lane-tile (branch-free, 16-way ILP).
DEVI u32 keep16(u32 ib) {
  u32 m16 = 0;
  #pragma unroll
  for (int c = 0; c < 4; ++c) {
    #pragma unroll
    for (int r = 0; r < 4; ++r) {
      m16 |= (u32)(tf_bits(42u, ib + (u32)(r * 2048 + c * 16)) >= KEEPC) << (c * 4 + r);
    }
  }
  return m16;
}

// Wave-balanced dropout draws for the kept positions of m16 (validated r3).
// dwp = this wave's 256-slot LDS worklist. Same-wave LDS round trip, no barrier.
DEVI u32 drop_balanced(u32 m16, u32 wb, int lane, u16* dwp) {
  const int cnt = __popc(m16);
  int pre = cnt;
  #pragma unroll
  for (int dlt = 1; dlt < 64; dlt <<= 1) {
    int t = __shfl_up(pre, dlt);
    if (lane >= dlt) pre += t;
  }
  const int total = __shfl(pre, 63);   // wave total kept (~102, max ~145)
  pre -= cnt;                          // exclusive prefix = this lane's first slot
  {
    u32 mm = m16; int jj = pre;
    while (mm) {
      const u32 s = (u32)__builtin_ctz(mm); mm &= mm - 1u;
      dwp[jj] = (u16)(((u32)lane << 4) | s);
      ++jj;
    }
  }
  for (int ws2 = lane; ws2 < total; ws2 += 64) {
    const u32 e = (u32)dwp[ws2];
    const u32 oo = e >> 4, ss = e & 15u;
    const u32 ii = wb + ((oo >> 4) * 4u + (ss & 3u)) * 2048u + (oo & 15u) + (ss >> 2) * 16u;
    dwp[ws2] = (u16)(e | ((u32)(tf_bits(7u, ii) < DROPC) << 15));
  }
  u32 d16 = 0;
  {
    u32 mm = m16; int jj = pre;
    while (mm) {
      const u32 s = (u32)__builtin_ctz(mm); mm &= mm - 1u;
      d16 |= (u32)((dwp[jj] >> 15) & 1u) << s;
      ++jj;
    }
  }
  return d16;
}

// ---------------- QKV projection GEMM (x @ W.T + b), fp32 in, bf16 MFMA ----------------
__global__ __launch_bounds__(256) void proj_kernel(
    const float* __restrict__ Xq, const float* __restrict__ Xk, const float* __restrict__ Xv,
    const float* __restrict__ Wq, const float* __restrict__ Wk, const float* __restrict__ Wv,
    const float* __restrict__ bq, const float* __restrict__ bk, const float* __restrict__ bv,
    u16* __restrict__ Qo, u16* __restrict__ Ko, u16* __restrict__ Vto)
{
  const int z = blockIdx.z;
  const float* X = (z == 0) ? Xq : (z == 1) ? Xk : Xv;
  const float* W = (z == 0) ? Wq : (z == 1) ? Wk : Wv;
  const float* bias = (z == 0) ? bq : (z == 1) ? bk : bv;
  const int m0 = blockIdx.x * 64, n0 = blockIdx.y * 64;
  const int tid = threadIdx.x, w = tid >> 6, lane = tid & 63, l = lane & 15, quad = lane >> 4;

  __shared__ __align__(16) u16 lsA[2048], lsB[2048];

  const int srow = tid >> 2, skp = tid & 3;
  const int sc = ((srow >> 4) * 64 + skp * 16 + (srow & 15)) * 8;
  const float* gA = X + (u32)(m0 + srow) * DMODEL + skp * 8;
  const float* gB = W + (u32)(n0 + srow) * DMODEL + skp * 8;

  f32x4 acc[2][2] = {};
  const int mh = (w >> 1) * 2, nh = (w & 1) * 2;

  for (int k0 = 0; k0 < DMODEL; k0 += 32) {
    short8 av  = cvt8(*(const float4*)(gA + k0), *(const float4*)(gA + k0 + 4));
    short8 bv8 = cvt8(*(const float4*)(gB + k0), *(const float4*)(gB + k0 + 4));
    __syncthreads();
    *(short8*)(lsA + sc) = av;
    *(short8*)(lsB + sc) = bv8;
    __syncthreads();
    short8 a0 = *(const short8*)(lsA + ((mh + 0) * 64 + lane) * 8);
    short8 a1 = *(const short8*)(lsA + ((mh + 1) * 64 + lane) * 8);
    short8 b0 = *(const short8*)(lsB + ((nh + 0) * 64 + lane) * 8);
    short8 b1 = *(const short8*)(lsB + ((nh + 1) * 64 + lane) * 8);
    acc[0][0] = __builtin_amdgcn_mfma_f32_16x16x32_bf16(a0, b0, acc[0][0], 0, 0, 0);
    acc[0][1] = __builtin_amdgcn_mfma_f32_16x16x32_bf16(a0, b1, acc[0][1], 0, 0, 0);
    acc[1][0] = __builtin_amdgcn_mfma_f32_16x16x32_bf16(a1, b0, acc[1][0], 0, 0, 0);
    acc[1][1] = __builtin_amdgcn_mfma_f32_16x16x32_bf16(a1, b1, acc[1][1], 0, 0, 0);
  }

  #pragma unroll
  for (int ma = 0; ma < 2; ++ma) {
    #pragma unroll
    for (int nb = 0; nb < 2; ++nb) {
      const int n = n0 + (nh + nb) * 16 + l;
      const float bval = bias[n];
      const int h = n >> 6, d = n & 63;
      #pragma unroll
      for (int r = 0; r < 4; ++r) {
        const int m = m0 + (mh + ma) * 16 + quad * 4 + r;
        float val = acc[ma][nb][r] + bval;
        if (z == 0) val *= 0.125f;              // fold 1/sqrt(dk) into Q
        const int b = m >> 11, s = m & 2047;
        if (z == 0)      Qo [((u32)(b * NHEAD + h) * S_LEN + s) * DK + d] = f2bf(val);
        else if (z == 1) Ko [((u32)(b * NHEAD + h) * S_LEN + s) * DK + d] = f2bf(val);
        else             Vto[((u32)(b * NHEAD + h) * DK + d) * S_LEN + s] = f2bf(val); // V transposed
      }
    }
  }
}

// ---------------- maskgen: all threefry draws at full ILP, no MFMA pressure ----------------
// One wave handles one (bh, qt, kt) 16q x 64k tile; lane's u32 = m16 | d16<<16,
// in exactly the per-lane MFMA C-layout the attention kernel consumes.
// Layout: M[((bh*128 + qt)*32 + kt)*64 + lane]. 16.8M u32 = 64 MiB.
__global__ __launch_bounds__(256) void maskgen_kernel(u32* __restrict__ Mout) {
  const int tid = threadIdx.x, w = tid >> 6, lane = tid & 63;
  const int l = lane & 15, quad = lane >> 4;
  __shared__ u16 dbuf[1024];                    // 4 waves x 256-slot worklist

  const u32 gw = (u32)blockIdx.x * 4u + (u32)w; // 0..262143
  const u32 kt = gw & 31u, qt = (gw >> 5) & 127u, bh = gw >> 12;
  const u32 ibase = (bh * 2048u + qt * 16u + (u32)quad * 4u) * 2048u + kt * 64u + (u32)l;
  const u32 wb    = (bh * 2048u + qt * 16u) * 2048u + kt * 64u;

  const u32 m16 = keep16(ibase);
  const u32 d16 = drop_balanced(m16, wb, lane, dbuf + w * 256);
  Mout[gw * 64u + (u32)lane] = m16 | (d16 << 16);
}

// ---------------- flash attention, PRECOMPUTED masks (r4 structure minus RNG) ----------------
__global__ __launch_bounds__(256) void attn_pre_kernel(
    const u16* __restrict__ Qs, const u16* __restrict__ Ks, const u16* __restrict__ Vts,
    const u32* __restrict__ Mask, u16* __restrict__ ctx)
{
  const int qb = blockIdx.x, bh = blockIdx.y;
  const int tid = threadIdx.x, w = tid >> 6, lane = tid & 63, l = lane & 15, quad = lane >> 4;

  __shared__ __align__(16) u16 KPf[4096];       // 8 KB: K frags, then per-wave P
  __shared__ __align__(16) u16 Vf[4096];        // 8 KB

  const int qrow0 = qb * 64 + w * 16;
  const u32 qbase = (u32)(bh * S_LEN + qrow0 + l) * DK + quad * 8;
  const short8 qa0 = *(const short8*)(Qs + qbase);
  const short8 qa1 = *(const short8*)(Qs + qbase + 32);

  f32x4 o[4] = {};
  float mr[4] = {NEG_INF, NEG_INF, NEG_INF, NEG_INF};
  float lr[4] = {0.f, 0.f, 0.f, 0.f};

  // staging maps (validated r2): LDS chunk = tid / tid+256, conflict-free
  const int kA  = ((tid >> 6) & 3) * 16 + (tid & 15);
  const int kdp = (tid >> 4) & 3;
  const u32 gk  = (u32)(bh * S_LEN + kA) * DK + kdp * 8;
  const int vd  = ((tid >> 7) & 1) * 16 + (tid & 15);
  const int vsp = ((tid >> 6) & 1) * 4 + ((tid >> 4) & 3);
  const u32 gvA = (u32)(bh * DK + vd) * S_LEN + vsp * 8;
  const u32 gvB = (u32)(bh * DK + vd + 32) * S_LEN + vsp * 8;

  // per-wave mask base: qt = qb*4 + w
  const u32* mb = Mask + ((u32)(bh * 128 + qb * 4 + w) * 32u) * 64u + (u32)lane;

  // P staging addresses (XOR-swizzled, conflict-free; validated r2)
  const int hi = l >> 3, j = l & 7;
  const int pb  = (hi * 128 + quad * 32 + j) ^ (((quad >> 1) << 3) | (hi << 4));
  const int prd = (lane * 8) ^ (lane & 24);
  u16* const pw = KPf + w * 1024;

  // prologue: tile-0 loads
  short8 k0v = *(const short8*)(Ks + gk);
  short8 k1v = *(const short8*)(Ks + gk + 32);
  short8 v0v = *(const short8*)(Vts + gvA);
  short8 v1v = *(const short8*)(Vts + gvB);
  u32 md = mb[0];

  for (int kt = 0; kt < 32; ++kt) {
    __syncthreads();                    // prev iter's P/V reads done
    *(short8*)(KPf + tid * 8) = k0v;
    *(short8*)(KPf + 2048 + tid * 8) = k1v;
    *(short8*)(Vf + tid * 8) = v0v;
    *(short8*)(Vf + 2048 + tid * 8) = v1v;
    __syncthreads();

    // hoist next tile's loads (full-iteration latency cover).
    // K/V: kt=31 reads one tile past -- still inside the 64 MB QKV region.
    // Mask: wrap kt+1 to 0 (value unused) to stay inside the mask buffer.
    {
      const u32 ko = (u32)(kt + 1) * 64u;
      k0v = *(const short8*)(Ks + gk + ko * DK);
      k1v = *(const short8*)(Ks + gk + ko * DK + 32);
      v0v = *(const short8*)(Vts + gvA + ko);
      v1v = *(const short8*)(Vts + gvB + ko);
    }
    const u32 mdn = mb[(u32)((kt + 1) & 31) * 64u];

    // S = Q K^T (16q x 64keys per wave)
    f32x4 sc4[4];
    #pragma unroll
    for (int nc = 0; nc < 4; ++nc) {
      short8 kb0 = *(const short8*)(KPf + (nc * 64 + lane) * 8);
      short8 kb1 = *(const short8*)(KPf + ((4 + nc) * 64 + lane) * 8);
      f32x4 zz = {0.f, 0.f, 0.f, 0.f};
      zz = __builtin_amdgcn_mfma_f32_16x16x32_bf16(qa0, kb0, zz, 0, 0, 0);
      sc4[nc] = __builtin_amdgcn_mfma_f32_16x16x32_bf16(qa1, kb1, zz, 0, 0, 0);
    }

    __syncthreads();                    // K fully consumed -> KPf reusable as P

    const u32 m16 = md & 0xffffu, d16 = md >> 16;
    #pragma unroll
    for (int r = 0; r < 4; ++r) {
      float v0 = ((m16 >> (r + 0))  & 1u) ? sc4[0][r] : NEG_INF;
      float v1 = ((m16 >> (r + 4))  & 1u) ? sc4[1][r] : NEG_INF;
      float v2 = ((m16 >> (r + 8))  & 1u) ? sc4[2][r] : NEG_INF;
      float v3 = ((m16 >> (r + 12)) & 1u) ? sc4[3][r] : NEG_INF;
      float mx = fmaxf(fmaxf(v0, v1), fmaxf(v2, v3));
      mx = fmaxf(mx, __shfl_xor(mx, 1));
      mx = fmaxf(mx, __shfl_xor(mx, 2));
      mx = fmaxf(mx, __shfl_xor(mx, 4));
      mx = fmaxf(mx, __shfl_xor(mx, 8));
      const float mn = fmaxf(mr[r], mx);
      const float mnc = fmaxf(mn, -1e37f);        // clamp: exp(-inf-mnc)=0
      const float alpha = __expf(mr[r] - mnc);    // mr=-inf -> 0 (o,lr are 0)
      mr[r] = mn;
      const float p0 = __expf(v0 - mnc);
      const float p1 = __expf(v1 - mnc);
      const float p2 = __expf(v2 - mnc);
      const float p3 = __expf(v3 - mnc);
      float rs = p0 + p1 + p2 + p3;
      rs += __shfl_xor(rs, 1);
      rs += __shfl_xor(rs, 2);
      rs += __shfl_xor(rs, 4);
      rs += __shfl_xor(rs, 8);
      lr[r] = alpha * lr[r] + rs;
      o[0][r] = o[0][r] * alpha; o[1][r] = o[1][r] * alpha;
      o[2][r] = o[2][r] * alpha; o[3][r] = o[3][r] * alpha;
      const float pd0 = ((d16 >> (r + 0))  & 1u) ? p0 * (1.f / 0.9f) : 0.f;
      const float pd1 = ((d16 >> (r + 4))  & 1u) ? p1 * (1.f / 0.9f) : 0.f;
      const float pd2 = ((d16 >> (r + 8))  & 1u) ? p2 * (1.f / 0.9f) : 0.f;
      const float pd3 = ((d16 >> (r + 12)) & 1u) ? p3 * (1.f / 0.9f) : 0.f;
      const int pi = pb ^ (r * 8);
      pw[pi      ] = f2bf(pd0);
      pw[pi + 256] = f2bf(pd1);
      pw[pi + 512] = f2bf(pd2);
      pw[pi + 768] = f2bf(pd3);
    }
    short8 pa0 = *(const short8*)(pw + prd);
    short8 pa1 = *(const short8*)(pw + 512 + prd);
    #pragma unroll
    for (int nd = 0; nd < 4; ++nd) {
      short8 vb0 = *(const short8*)(Vf + ((nd * 2 + 0) * 64 + lane) * 8);
      short8 vb1 = *(const short8*)(Vf + ((nd * 2 + 1) * 64 + lane) * 8);
      o[nd] = __builtin_amdgcn_mfma_f32_16x16x32_bf16(pa0, vb0, o[nd], 0, 0, 0);
      o[nd] = __builtin_amdgcn_mfma_f32_16x16x32_bf16(pa1, vb1, o[nd], 0, 0, 0);
    }
    md = mdn;
  }

  const int b = bh >> 4, h = bh & 15;
  #pragma unroll
  for (int r = 0; r < 4; ++r) {
    const float inv = 1.f / lr[r];
    const int qrow = qb * 64 + w * 16 + quad * 4 + r;
    const u32 ob = (u32)(b * S_LEN + qrow) * DMODEL + h * DK;
    ctx[ob + 0  + l] = f2bf(o[0][r] * inv);
    ctx[ob + 16 + l] = f2bf(o[1][r] * inv);
    ctx[ob + 32 + l] = f2bf(o[2][r] * inv);
    ctx[ob + 48 + l] = f2bf(o[3][r] * inv);
  }
}

// ---------------- fallback: r4 attention with inline RNG (known-good 831 us) ----------------
__global__ __launch_bounds__(256) void attn_rng_kernel(
    const u16* __restrict__ Qs, const u16* __restrict__ Ks, const u16* __restrict__ Vts,
    u16* __restrict__ ctx)
{
  const int qb = blockIdx.x, bh = blockIdx.y;
  const int tid = threadIdx.x, w = tid >> 6, lane = tid & 63, l = lane & 15, quad = lane >> 4;

  __shared__ __align__(16) u16 KPf[4096];
  __shared__ __align__(16) u16 Vf[4096];
  __shared__ __align__(16) u16 dbuf[1024];

  const int qrow0 = qb * 64 + w * 16;
  const u32 qbase = (u32)(bh * S_LEN + qrow0 + l) * DK + quad * 8;
  const short8 qa0 = *(const short8*)(Qs + qbase);
  const short8 qa1 = *(const short8*)(Qs + qbase + 32);

  u32 ibase = ((u32)bh * 2048u + (u32)(qrow0 + quad * 4)) * 2048u + (u32)l;
  const u32 wb0 = ((u32)bh * 2048u + (u32)qrow0) * 2048u;
  u16* const dwp = dbuf + w * 256;

  f32x4 o[4] = {};
  float mr[4] = {NEG_INF, NEG_INF, NEG_INF, NEG_INF};
  float lr[4] = {0.f, 0.f, 0.f, 0.f};

  const int kA  = ((tid >> 6) & 3) * 16 + (tid & 15);
  const int kdp = (tid >> 4) & 3;
  const u32 gk  = (u32)(bh * S_LEN + kA) * DK + kdp * 8;
  const int vd  = ((tid >> 7) & 1) * 16 + (tid & 15);
  const int vsp = ((tid >> 6) & 1) * 4 + ((tid >> 4) & 3);
  const u32 gvA = (u32)(bh * DK + vd) * S_LEN + vsp * 8;
  const u32 gvB = (u32)(bh * DK + vd + 32) * S_LEN + vsp * 8;

  const int hi = l >> 3, j = l & 7;
  const int pxor = ((quad >> 1) << 3) | (hi << 4);
  const int pb = (hi * 128 + quad * 32 + j) ^ pxor;
  const int prd = (lane * 8) ^ (lane & 24);
  u16* const pw = KPf + w * 1024;

  short8 k0v = *(const short8*)(Ks + gk);
  short8 k1v = *(const short8*)(Ks + gk + 32);
  short8 v0v = *(const short8*)(Vts + gvA);
  short8 v1v = *(const short8*)(Vts + gvB);
  u32 m16 = keep16(ibase);
  u32 d16 = drop_balanced(m16, wb0, lane, dwp);
  ibase += 64u;

  for (int kt = 0; kt < 32; ++kt) {
    __syncthreads();
    *(short8*)(KPf + tid * 8) = k0v;
    *(short8*)(KPf + 2048 + tid * 8) = k1v;
    *(short8*)(Vf + tid * 8) = v0v;
    *(short8*)(Vf + 2048 + tid * 8) = v1v;
    __syncthreads();

    {
      const u32 ko = (u32)(kt + 1) * 64u;
      k0v = *(const short8*)(Ks + gk + ko * DK);
      k1v = *(const short8*)(Ks + gk + ko * DK + 32);
      v0v = *(const short8*)(Vts + gvA + ko);
      v1v = *(const short8*)(Vts + gvB + ko);
    }

    f32x4 sc4[4];
    #pragma unroll
    for (int nc = 0; nc < 4; ++nc) {
      short8 kb0 = *(const short8*)(KPf + (nc * 64 + lane) * 8);
      short8 kb1 = *(const short8*)(KPf + ((4 + nc) * 64 + lane) * 8);
      f32x4 zz = {0.f, 0.f, 0.f, 0.f};
      zz = __builtin_amdgcn_mfma_f32_16x16x32_bf16(qa0, kb0, zz, 0, 0, 0);
      sc4[nc] = __builtin_amdgcn_mfma_f32_16x16x32_bf16(qa1, kb1, zz, 0, 0, 0);
    }
    const u32 m16n = keep16(ibase);

    __syncthreads();

    #pragma unroll
    for (int r = 0; r < 4; ++r) {
      float v0 = ((m16 >> (r + 0))  & 1u) ? sc4[0][r] : NEG_INF;
      float v1 = ((m16 >> (r + 4))  & 1u) ? sc4[1][r] : NEG_INF;
      float v2 = ((m16 >> (r + 8))  & 1u) ? sc4[2][r] : NEG_INF;
      float v3 = ((m16 >> (r + 12)) & 1u) ? sc4[3][r] : NEG_INF;
      float mx = fmaxf(fmaxf(v0, v1), fmaxf(v2, v3));
      mx = fmaxf(mx, __shfl_xor(mx, 1));
      mx = fmaxf(mx, __shfl_xor(mx, 2));
      mx = fmaxf(mx, __shfl_xor(mx, 4));
      mx = fmaxf(mx, __shfl_xor(mx, 8));
      const float mn = fmaxf(mr[r], mx);
      const float mnc = fmaxf(mn, -1e37f);
      const float alpha = __expf(mr[r] - mnc);
      mr[r] = mn;
      const float p0 = __expf(v0 - mnc);
      const float p1 = __expf(v1 - mnc);
      const float p2 = __expf(v2 - mnc);
      const float p3 = __expf(v3 - mnc);
      float rs = p0 + p1 + p2 + p3;
      rs += __shfl_xor(rs, 1);
      rs += __shfl_xor(rs, 2);
      rs += __shfl_xor(rs, 4);
      rs += __shfl_xor(rs, 8);
      lr[r] = alpha * lr[r] + rs;
      o[0][r] = o[0][r] * alpha; o[1][r] = o[1][r] * alpha;
      o[2][r] = o[2][r] * alpha; o[3][r] = o[3][r] * alpha;
      const float pd0 = ((d16 >> (r + 0))  & 1u) ? p0 * (1.f / 0.9f) : 0.f;
      const float pd1 = ((d16 >> (r + 4))  & 1u) ? p1 * (1.f / 0.9f) : 0.f;
      const float pd2 = ((d16 >> (r + 8))  & 1u) ? p2 * (1.f / 0.9f) : 0.f;
      const float pd3 = ((d16 >> (r + 12)) & 1u) ? p3 * (1.f / 0.9f) : 0.f;
      const int pi = pb ^ (r * 8);
      pw[pi      ] = f2bf(pd0);
      pw[pi + 256] = f2bf(pd1);
      pw[pi + 512] = f2bf(pd2);
      pw[pi + 768] = f2bf(pd3);
    }
    short8 pa0 = *(const short8*)(pw + prd);
    short8 pa1 = *(const short8*)(pw + 512 + prd);
    #pragma unroll
    for (int nd = 0; nd < 4; ++nd) {
      short8 vb0 = *(const short8*)(Vf + ((nd * 2 + 0) * 64 + lane) * 8);
      short8 vb1 = *(const short8*)(Vf + ((nd * 2 + 1) * 64 + lane) * 8);
      o[nd] = __builtin_amdgcn_mfma_f32_16x16x32_bf16(pa0, vb0, o[nd], 0, 0, 0);
      o[nd] = __builtin_amdgcn_mfma_f32_16x16x32_bf16(pa1, vb1, o[nd], 0, 0, 0);
    }

    u32 d16n = 0;
    if (kt < 31) d16n = drop_balanced(m16n, wb0 + (u32)(kt + 1) * 64u, lane, dwp);
    m16 = m16n; d16 = d16n;
    ibase += 64u;
  }

  const int b = bh >> 4, h = bh & 15;
  #pragma unroll
  for (int r = 0; r < 4; ++r) {
    const float inv = 1.f / lr[r];
    const int qrow = qb * 64 + w * 16 + quad * 4 + r;
    const u32 ob = (u32)(b * S_LEN + qrow) * DMODEL + h * DK;
    ctx[ob + 0  + l] = f2bf(o[0][r] * inv);
    ctx[ob + 16 + l] = f2bf(o[1][r] * inv);
    ctx[ob + 32 + l] = f2bf(o[2][r] * inv);
    ctx[ob + 48 + l] = f2bf(o[3][r] * inv);
  }
}

// ---------------- output projection (ctx @ Wo.T + bo) ----------------
__global__ __launch_bounds__(256) void oproj_kernel(
    const u16* __restrict__ X, const float* __restrict__ W, const float* __restrict__ bias,
    float* __restrict__ out)
{
  const int m0 = blockIdx.x * 64, n0 = blockIdx.y * 64;
  const int tid = threadIdx.x, w = tid >> 6, lane = tid & 63, l = lane & 15, quad = lane >> 4;

  __shared__ __align__(16) u16 lsA[2048], lsB[2048];

  const int srow = tid >> 2, skp = tid & 3;
  const int sc = ((srow >> 4) * 64 + skp * 16 + (srow & 15)) * 8;
  const u16*  gA = X + (u32)(m0 + srow) * DMODEL + skp * 8;
  const float* gB = W + (u32)(n0 + srow) * DMODEL + skp * 8;

  f32x4 acc[2][2] = {};
  const int mh = (w >> 1) * 2, nh = (w & 1) * 2;

  for (int k0 = 0; k0 < DMODEL; k0 += 32) {
    short8 av  = *(const short8*)(gA + k0);
    short8 bv8 = cvt8(*(const float4*)(gB + k0), *(const float4*)(gB + k0 + 4));
    __syncthreads();
    *(short8*)(lsA + sc) = av;
    *(short8*)(lsB + sc) = bv8;
    __syncthreads();
    short8 a0 = *(const short8*)(lsA + ((mh + 0) * 64 + lane) * 8);
    short8 a1 = *(const short8*)(lsA + ((mh + 1) * 64 + lane) * 8);
    short8 b0 = *(const short8*)(lsB + ((nh + 0) * 64 + lane) * 8);
    short8 b1 = *(const short8*)(lsB + ((nh + 1) * 64 + lane) * 8);
    acc[0][0] = __builtin_amdgcn_mfma_f32_16x16x32_bf16(a0, b0, acc[0][0], 0, 0, 0);
    acc[0][1] = __builtin_amdgcn_mfma_f32_16x16x32_bf16(a0, b1, acc[0][1], 0, 0, 0);
    acc[1][0] = __builtin_amdgcn_mfma_f32_16x16x32_bf16(a1, b0, acc[1][0], 0, 0, 0);
    acc[1][1] = __builtin_amdgcn_mfma_f32_16x16x32_bf16(a1, b1, acc[1][1], 0, 0, 0);
  }

  #pragma unroll
  for (int ma = 0; ma < 2; ++ma) {
    #pragma unroll
    for (int nb = 0; nb < 2; ++nb) {
      const int n = n0 + (nh + nb) * 16 + l;
      const float bval = bias[n];
      #pragma unroll
      for (int r = 0; r < 4; ++r) {
        const int m = m0 + (mh + ma) * 16 + quad * 4 + r;
        out[(u32)m * DMODEL + n] = acc[ma][nb][r] + bval;
      }
    }
  }
}

extern "C" void kernel_launch(void* const* d_in, const int* in_sizes, int n_in,
                              void* d_out, int out_size, void* d_ws, size_t ws_size,
                              hipStream_t stream) {
  (void)in_sizes; (void)n_in; (void)out_size;
  const float* q  = (const float*)d_in[0];
  const float* k  = (const float*)d_in[1];
  const float* v  = (const float*)d_in[2];
  const float* Wq = (const float*)d_in[3];
  const float* bq = (const float*)d_in[4];
  const float* Wk = (const float*)d_in[5];
  const float* bk = (const float*)d_in[6];
  const float* Wv = (const float*)d_in[7];
  const float* bv = (const float*)d_in[8];
  const float* Wo = (const float*)d_in[9];
  const float* bo = (const float*)d_in[10];

  char* ws = (char*)d_ws;
  u16* Qs   = (u16*)(ws);                 // [bh][s][dk] bf16, pre-scaled 1/8 (16 MB)
  u16* Ks   = (u16*)(ws + 16777216);      // [bh][s][dk]
  u16* Vts  = (u16*)(ws + 33554432);      // [bh][dk][s]  (transposed)
  u16* ctx  = (u16*)(ws + 50331648);      // [b][s][h*dk]
  u32* Mask = (u32*)(ws + 67108864);      // [bh][qt][kt][lane] m16|d16<<16 (64 MiB)

  proj_kernel<<<dim3(128, 16, 3), 256, 0, stream>>>(q, k, v, Wq, Wk, Wv,
                                                    bq, bk, bv, Qs, Ks, Vts);
  if (ws_size >= (size_t)134217728) {
    maskgen_kernel<<<65536, 256, 0, stream>>>(Mask);
    attn_pre_kernel<<<dim3(32, 64), 256, 0, stream>>>(Qs, Ks, Vts, Mask, ctx);
  } else {
    attn_rng_kernel<<<dim3(32, 64), 256, 0, stream>>>(Qs, Ks, Vts, ctx);
  }
  oproj_kernel<<<dim3(128, 16), 256, 0, stream>>>(ctx, Wo, bo, (float*)d_out);
}

// Round 10
// 1107.270 us; speedup vs baseline: 1.0368x; 1.0368x over previous
//
#include <hip/hip_runtime.h>
#include <stdint.h>

typedef unsigned short u16;
typedef unsigned int u32;
typedef __attribute__((ext_vector_type(8))) short short8;   // 8 x bf16 (4 VGPRs)
typedef __attribute__((ext_vector_type(4))) float f32x4;

#define DEVI static __device__ __forceinline__

#define S_LEN 2048
#define DMODEL 1024
#define NHEAD 16
#define DK 64
#define NEG_INF (-__builtin_inff())
// u = bitcast((bits>>9)|0x3f800000)-1; boundary 0.9f = 7549747/2^23
// keep:   u > 0.9  <=> bits >= 7549748*512
// dropout keep: u < 0.9  <=> bits <  7549747*512
#define KEEPC 3865470976u
#define DROPC 3865470464u

DEVI u16 f2bf(float f) {
  u32 u = __builtin_bit_cast(u32, f);
  u32 r = u + 0x7fffu + ((u >> 16) & 1u);   // RNE
  return (u16)(r >> 16);
}

DEVI short8 cvt8(float4 a, float4 b) {
  short8 r;
  r[0] = (short)f2bf(a.x); r[1] = (short)f2bf(a.y);
  r[2] = (short)f2bf(a.z); r[3] = (short)f2bf(a.w);
  r[4] = (short)f2bf(b.x); r[5] = (short)f2bf(b.y);
  r[6] = (short)f2bf(b.z); r[7] = (short)f2bf(b.w);
  return r;
}

// JAX threefry2x32 (20 rounds), partitionable draw (default since jax 0.4.36):
// key (0,key), ctr (0,i), bits = o0 ^ o1. key is compile-time const at call
// sites -> K2 and injections fold. Validated bit-exact in rounds 2/3.
DEVI u32 tf_bits(u32 key, u32 i) {
  const u32 K2 = key ^ 0x1BD11BDAu;
  u32 x0 = 0u, x1 = i + key;
#define TFR(r) { x0 += x1; x1 = __builtin_rotateleft32(x1, r); x1 ^= x0; }
  TFR(13) TFR(15) TFR(26) TFR(6)  x0 += key; x1 += K2 + 1u;
  TFR(17) TFR(29) TFR(16) TFR(24) x0 += K2;  x1 += 2u;
  TFR(13) TFR(15) TFR(26) TFR(6)  /*x0+=0*/  x1 += key + 3u;
  TFR(17) TFR(29) TFR(16) TFR(24) x0 += key; x1 += K2 + 4u;
  TFR(13) TFR(15) TFR(26) TFR(6)  x0 += K2;  x1 += 5u;
#undef TFR
  return x0 ^ x1;
}

// 16 keep draws for one 16q x 64k lane-tile (branch-free; meant to be merged
// by the scheduler into MFMA/ds_read stall regions of the SAME basic block).
DEVI u32 keep16(u32 ib) {
  u32 m16 = 0;
  #pragma unroll
  for (int c = 0; c < 4; ++c) {
    #pragma unroll
    for (int r = 0; r < 4; ++r) {
      m16 |= (u32)(tf_bits(42u, ib + (u32)(r * 2048 + c * 16)) >= KEEPC) << (c * 4 + r);
    }
  }
  return m16;
}

// Wave-balanced dropout draws for the kept positions of m16 (validated r3).
// dwp = this wave's 256-slot LDS worklist. Same-wave LDS round trip, no barrier.
DEVI u32 drop_balanced(u32 m16, u32 wb, int lane, u16* dwp) {
  const int cnt = __popc(m16);
  int pre = cnt;
  #pragma unroll
  for (int dlt = 1; dlt < 64; dlt <<= 1) {
    int t = __shfl_up(pre, dlt);
    if (lane >= dlt) pre += t;
  }
  const int total = __shfl(pre, 63);   // wave total kept (~102, max ~145)
  pre -= cnt;                          // exclusive prefix = this lane's first slot
  {
    u32 mm = m16; int jj = pre;
    while (mm) {
      const u32 s = (u32)__builtin_ctz(mm); mm &= mm - 1u;
      dwp[jj] = (u16)(((u32)lane << 4) | s);
      ++jj;
    }
  }
  for (int ws2 = lane; ws2 < total; ws2 += 64) {
    const u32 e = (u32)dwp[ws2];
    const u32 oo = e >> 4, ss = e & 15u;
    const u32 ii = wb + ((oo >> 4) * 4u + (ss & 3u)) * 2048u + (oo & 15u) + (ss >> 2) * 16u;
    dwp[ws2] = (u16)(e | ((u32)(tf_bits(7u, ii) < DROPC) << 15));
  }
  u32 d16 = 0;
  {
    u32 mm = m16; int jj = pre;
    while (mm) {
      const u32 s = (u32)__builtin_ctz(mm); mm &= mm - 1u;
      d16 |= (u32)((dwp[jj] >> 15) & 1u) << s;
      ++jj;
    }
  }
  return d16;
}

// ---------------- QKV projection GEMM (x @ W.T + b), fp32 in, bf16 MFMA ----------------
// 64x64 tile / block, 4 waves (2x2), each wave 32x32 via 4 C-frags.
// LDS frag-major: chunk c = fragblk*64+lane holds T[row=fragblk*16+(lane&15)][k=(lane>>4)*8..+7]
__global__ __launch_bounds__(256) void proj_kernel(
    const float* __restrict__ Xq, const float* __restrict__ Xk, const float* __restrict__ Xv,
    const float* __restrict__ Wq, const float* __restrict__ Wk, const float* __restrict__ Wv,
    const float* __restrict__ bq, const float* __restrict__ bk, const float* __restrict__ bv,
    u16* __restrict__ Qo, u16* __restrict__ Ko, u16* __restrict__ Vto)
{
  const int z = blockIdx.z;
  const float* X = (z == 0) ? Xq : (z == 1) ? Xk : Xv;
  const float* W = (z == 0) ? Wq : (z == 1) ? Wk : Wv;
  const float* bias = (z == 0) ? bq : (z == 1) ? bk : bv;
  const int m0 = blockIdx.x * 64, n0 = blockIdx.y * 64;
  const int tid = threadIdx.x, w = tid >> 6, lane = tid & 63, l = lane & 15, quad = lane >> 4;

  __shared__ __align__(16) u16 lsA[2048], lsB[2048];

  const int srow = tid >> 2, skp = tid & 3;
  const int sc = ((srow >> 4) * 64 + skp * 16 + (srow & 15)) * 8;
  const float* gA = X + (u32)(m0 + srow) * DMODEL + skp * 8;
  const float* gB = W + (u32)(n0 + srow) * DMODEL + skp * 8;

  f32x4 acc[2][2] = {};
  const int mh = (w >> 1) * 2, nh = (w & 1) * 2;

  for (int k0 = 0; k0 < DMODEL; k0 += 32) {
    short8 av  = cvt8(*(const float4*)(gA + k0), *(const float4*)(gA + k0 + 4));
    short8 bv8 = cvt8(*(const float4*)(gB + k0), *(const float4*)(gB + k0 + 4));
    __syncthreads();
    *(short8*)(lsA + sc) = av;
    *(short8*)(lsB + sc) = bv8;
    __syncthreads();
    short8 a0 = *(const short8*)(lsA + ((mh + 0) * 64 + lane) * 8);
    short8 a1 = *(const short8*)(lsA + ((mh + 1) * 64 + lane) * 8);
    short8 b0 = *(const short8*)(lsB + ((nh + 0) * 64 + lane) * 8);
    short8 b1 = *(const short8*)(lsB + ((nh + 1) * 64 + lane) * 8);
    acc[0][0] = __builtin_amdgcn_mfma_f32_16x16x32_bf16(a0, b0, acc[0][0], 0, 0, 0);
    acc[0][1] = __builtin_amdgcn_mfma_f32_16x16x32_bf16(a0, b1, acc[0][1], 0, 0, 0);
    acc[1][0] = __builtin_amdgcn_mfma_f32_16x16x32_bf16(a1, b0, acc[1][0], 0, 0, 0);
    acc[1][1] = __builtin_amdgcn_mfma_f32_16x16x32_bf16(a1, b1, acc[1][1], 0, 0, 0);
  }

  #pragma unroll
  for (int ma = 0; ma < 2; ++ma) {
    #pragma unroll
    for (int nb = 0; nb < 2; ++nb) {
      const int n = n0 + (nh + nb) * 16 + l;
      const float bval = bias[n];
      const int h = n >> 6, d = n & 63;
      #pragma unroll
      for (int r = 0; r < 4; ++r) {
        const int m = m0 + (mh + ma) * 16 + quad * 4 + r;
        float val = acc[ma][nb][r] + bval;
        if (z == 0) val *= 0.125f;              // fold 1/sqrt(dk) into Q
        const int b = m >> 11, s = m & 2047;
        if (z == 0)      Qo [((u32)(b * NHEAD + h) * S_LEN + s) * DK + d] = f2bf(val);
        else if (z == 1) Ko [((u32)(b * NHEAD + h) * S_LEN + s) * DK + d] = f2bf(val);
        else             Vto[((u32)(b * NHEAD + h) * DK + d) * S_LEN + s] = f2bf(val); // V transposed
      }
    }
  }
}

// ---------------- flash attention with INLINE threefry mask + dropout ----------------
// Round-4 structure (byte-exact revert; last passing kernel, 831 us):
//   - keep-draws(kt+1) computed inside the QK^T region (fills ds/MFMA waits)
//   - global K/V loads hoisted one tile ahead (full-iteration latency cover)
//   - dropout-balance(kt+1) after PV, off the critical path
//   - NEG_INF cndmasks replaced by one clamp: exp(x - max(mn,-1e37)) is 0 for
//     masked lanes and handles the all-masked row (o=lr=0 so alpha irrelevant)
// r7/r8/r9 NOTE: the atomicOr-readback + Pf-separate 2-barrier + worklist-
// aliased-into-P rework deterministically inflated absmax 0.0039->0.028 across
// three variants while every numerical suspect was eliminated one at a time.
// Offline analysis found no flaw; do NOT reintroduce without on-device
// isolation of the transport path alone.
__global__ __launch_bounds__(256) void attn_kernel(
    const u16* __restrict__ Qs, const u16* __restrict__ Ks, const u16* __restrict__ Vts,
    u16* __restrict__ ctx)
{
  const int qb = blockIdx.x, bh = blockIdx.y;
  const int tid = threadIdx.x, w = tid >> 6, lane = tid & 63, l = lane & 15, quad = lane >> 4;

  __shared__ __align__(16) u16 KPf[4096];       // 8 KB: K frags, then per-wave P
  __shared__ __align__(16) u16 Vf[4096];        // 8 KB
  __shared__ __align__(16) u16 dbuf[1024];      // 2 KB: per-wave 256-slot dropout worklist

  // Q A-frags, preloaded (Q pre-scaled by 1/8)
  const int qrow0 = qb * 64 + w * 16;
  const u32 qbase = (u32)(bh * S_LEN + qrow0 + l) * DK + quad * 8;
  const short8 qa0 = *(const short8*)(Qs + qbase);
  const short8 qa1 = *(const short8*)(Qs + qbase + 32);

  // per-lane RNG base: rows start at qrow0+quad*4, col offset l (within tile)
  u32 ibase = ((u32)bh * 2048u + (u32)(qrow0 + quad * 4)) * 2048u + (u32)l;
  // wave-uniform tile base for worker-side index reconstruction
  const u32 wb0 = ((u32)bh * 2048u + (u32)qrow0) * 2048u;
  u16* const dwp = dbuf + w * 256;

  f32x4 o[4] = {};
  float mr[4] = {NEG_INF, NEG_INF, NEG_INF, NEG_INF};
  float lr[4] = {0.f, 0.f, 0.f, 0.f};

  // ---- staging maps: LDS chunk = tid (and tid+256), global derived by inverse map ----
  const int kA  = ((tid >> 6) & 3) * 16 + (tid & 15);
  const int kdp = (tid >> 4) & 3;
  const u32 gk  = (u32)(bh * S_LEN + kA) * DK + kdp * 8;
  const int vd  = ((tid >> 7) & 1) * 16 + (tid & 15);
  const int vsp = ((tid >> 6) & 1) * 4 + ((tid >> 4) & 3);
  const u32 gvA = (u32)(bh * DK + vd) * S_LEN + vsp * 8;
  const u32 gvB = (u32)(bh * DK + vd + 32) * S_LEN + vsp * 8;

  // P staging addresses (swizzled, conflict-free)
  const int hi = l >> 3, j = l & 7;
  const int pxor = ((quad >> 1) << 3) | (hi << 4);
  const int pb = (hi * 128 + quad * 32 + j) ^ pxor;     // r==0 base; bits 3,4 free for r
  const int prd = (lane * 8) ^ (lane & 24);             // swizzled read chunk offset
  u16* const pw = KPf + w * 1024;

  // ---- prologue: loads + RNG for tile 0 ----
  short8 k0v = *(const short8*)(Ks + gk);
  short8 k1v = *(const short8*)(Ks + gk + 32);
  short8 v0v = *(const short8*)(Vts + gvA);
  short8 v1v = *(const short8*)(Vts + gvB);
  u32 m16 = keep16(ibase);
  u32 d16 = drop_balanced(m16, wb0, lane, dwp);
  ibase += 64u;

  for (int kt = 0; kt < 32; ++kt) {
    __syncthreads();                    // prev iter's P/V reads done
    *(short8*)(KPf + tid * 8) = k0v;            // chunk tid        (linear, conflict-free)
    *(short8*)(KPf + 2048 + tid * 8) = k1v;     // chunk tid+256
    *(short8*)(Vf + tid * 8) = v0v;
    *(short8*)(Vf + 2048 + tid * 8) = v1v;
    __syncthreads();

    // issue next tile's loads now: a full iteration of latency cover.
    // kt=31 reads one tile past Ks/Vts ends -- still inside the 64 MB
    // workspace (never staged/used), so no fault and no clamp needed.
    {
      const u32 ko = (u32)(kt + 1) * 64u;
      k0v = *(const short8*)(Ks + gk + ko * DK);
      k1v = *(const short8*)(Ks + gk + ko * DK + 32);
      v0v = *(const short8*)(Vts + gvA + ko);
      v1v = *(const short8*)(Vts + gvB + ko);
    }

    // S = Q K^T (16q x 64keys per wave), with next tile's keep-draws merged
    // into the same region as VALU filler for the ds_read/MFMA waits.
    f32x4 sc4[4];
    #pragma unroll
    for (int nc = 0; nc < 4; ++nc) {
      short8 kb0 = *(const short8*)(KPf + (nc * 64 + lane) * 8);
      short8 kb1 = *(const short8*)(KPf + ((4 + nc) * 64 + lane) * 8);
      f32x4 zz = {0.f, 0.f, 0.f, 0.f};
      zz = __builtin_amdgcn_mfma_f32_16x16x32_bf16(qa0, kb0, zz, 0, 0, 0);
      sc4[nc] = __builtin_amdgcn_mfma_f32_16x16x32_bf16(qa1, kb1, zz, 0, 0, 0);
    }
    const u32 m16n = keep16(ibase);     // tile kt+1 (kt=31: harmless filler)

    __syncthreads();                    // K fully consumed -> KPf reusable as P

    #pragma unroll
    for (int r = 0; r < 4; ++r) {
      float v0 = ((m16 >> (r + 0))  & 1u) ? sc4[0][r] : NEG_INF;
      float v1 = ((m16 >> (r + 4))  & 1u) ? sc4[1][r] : NEG_INF;
      float v2 = ((m16 >> (r + 8))  & 1u) ? sc4[2][r] : NEG_INF;
      float v3 = ((m16 >> (r + 12)) & 1u) ? sc4[3][r] : NEG_INF;
      float mx = fmaxf(fmaxf(v0, v1), fmaxf(v2, v3));
      mx = fmaxf(mx, __shfl_xor(mx, 1));
      mx = fmaxf(mx, __shfl_xor(mx, 2));
      mx = fmaxf(mx, __shfl_xor(mx, 4));
      mx = fmaxf(mx, __shfl_xor(mx, 8));
      const float mn = fmaxf(mr[r], mx);
      const float mnc = fmaxf(mn, -1e37f);        // clamp: exp(-inf-mnc)=0
      const float alpha = __expf(mr[r] - mnc);    // mr=-inf -> 0 (o,lr are 0)
      mr[r] = mn;
      const float p0 = __expf(v0 - mnc);
      const float p1 = __expf(v1 - mnc);
      const float p2 = __expf(v2 - mnc);
      const float p3 = __expf(v3 - mnc);
      float rs = p0 + p1 + p2 + p3;
      rs += __shfl_xor(rs, 1);
      rs += __shfl_xor(rs, 2);
      rs += __shfl_xor(rs, 4);
      rs += __shfl_xor(rs, 8);
      lr[r] = alpha * lr[r] + rs;
      o[0][r] = o[0][r] * alpha; o[1][r] = o[1][r] * alpha;
      o[2][r] = o[2][r] * alpha; o[3][r] = o[3][r] * alpha;
      // dropout (denominator uses undropped p; numerator uses p*dbit/0.9)
      const float pd0 = ((d16 >> (r + 0))  & 1u) ? p0 * (1.f / 0.9f) : 0.f;
      const float pd1 = ((d16 >> (r + 4))  & 1u) ? p1 * (1.f / 0.9f) : 0.f;
      const float pd2 = ((d16 >> (r + 8))  & 1u) ? p2 * (1.f / 0.9f) : 0.f;
      const float pd3 = ((d16 >> (r + 12)) & 1u) ? p3 * (1.f / 0.9f) : 0.f;
      // write P in A-frag layout (bank-conflict-free via XOR swizzle)
      const int pi = pb ^ (r * 8);
      pw[pi      ] = f2bf(pd0);   // keys  0..15
      pw[pi + 256] = f2bf(pd1);   // keys 16..31
      pw[pi + 512] = f2bf(pd2);   // keys 32..47
      pw[pi + 768] = f2bf(pd3);   // keys 48..63
    }
    // same-wave LDS round-trip: read P as A-frags (swizzled chunk order)
    short8 pa0 = *(const short8*)(pw + prd);
    short8 pa1 = *(const short8*)(pw + 512 + prd);
    #pragma unroll
    for (int nd = 0; nd < 4; ++nd) {
      short8 vb0 = *(const short8*)(Vf + ((nd * 2 + 0) * 64 + lane) * 8);
      short8 vb1 = *(const short8*)(Vf + ((nd * 2 + 1) * 64 + lane) * 8);
      o[nd] = __builtin_amdgcn_mfma_f32_16x16x32_bf16(pa0, vb0, o[nd], 0, 0, 0);
      o[nd] = __builtin_amdgcn_mfma_f32_16x16x32_bf16(pa1, vb1, o[nd], 0, 0, 0);
    }

    // dropout-balance for tile kt+1 (off critical path; dbuf is wave-private)
    u32 d16n = 0;
    if (kt < 31) d16n = drop_balanced(m16n, wb0 + (u32)(kt + 1) * 64u, lane, dwp);
    m16 = m16n; d16 = d16n;
    ibase += 64u;
  }

  const int b = bh >> 4, h = bh & 15;
  #pragma unroll
  for (int r = 0; r < 4; ++r) {
    const float inv = 1.f / lr[r];
    const int qrow = qb * 64 + w * 16 + quad * 4 + r;
    const u32 ob = (u32)(b * S_LEN + qrow) * DMODEL + h * DK;
    ctx[ob + 0  + l] = f2bf(o[0][r] * inv);
    ctx[ob + 16 + l] = f2bf(o[1][r] * inv);
    ctx[ob + 32 + l] = f2bf(o[2][r] * inv);
    ctx[ob + 48 + l] = f2bf(o[3][r] * inv);
  }
}

// ---------------- output projection (ctx @ Wo.T + bo), bf16 A, fp32 B-in, fp32 out ----------------
__global__ __launch_bounds__(256) void oproj_kernel(
    const u16* __restrict__ X, const float* __restrict__ W, const float* __restrict__ bias,
    float* __restrict__ out)
{
  const int m0 = blockIdx.x * 64, n0 = blockIdx.y * 64;
  const int tid = threadIdx.x, w = tid >> 6, lane = tid & 63, l = lane & 15, quad = lane >> 4;

  __shared__ __align__(16) u16 lsA[2048], lsB[2048];

  const int srow = tid >> 2, skp = tid & 3;
  const int sc = ((srow >> 4) * 64 + skp * 16 + (srow & 15)) * 8;
  const u16*  gA = X + (u32)(m0 + srow) * DMODEL + skp * 8;
  const float* gB = W + (u32)(n0 + srow) * DMODEL + skp * 8;

  f32x4 acc[2][2] = {};
  const int mh = (w >> 1) * 2, nh = (w & 1) * 2;

  for (int k0 = 0; k0 < DMODEL; k0 += 32) {
    short8 av  = *(const short8*)(gA + k0);
    short8 bv8 = cvt8(*(const float4*)(gB + k0), *(const float4*)(gB + k0 + 4));
    __syncthreads();
    *(short8*)(lsA + sc) = av;
    *(short8*)(lsB + sc) = bv8;
    __syncthreads();
    short8 a0 = *(const short8*)(lsA + ((mh + 0) * 64 + lane) * 8);
    short8 a1 = *(const short8*)(lsA + ((mh + 1) * 64 + lane) * 8);
    short8 b0 = *(const short8*)(lsB + ((nh + 0) * 64 + lane) * 8);
    short8 b1 = *(const short8*)(lsB + ((nh + 1) * 64 + lane) * 8);
    acc[0][0] = __builtin_amdgcn_mfma_f32_16x16x32_bf16(a0, b0, acc[0][0], 0, 0, 0);
    acc[0][1] = __builtin_amdgcn_mfma_f32_16x16x32_bf16(a0, b1, acc[0][1], 0, 0, 0);
    acc[1][0] = __builtin_amdgcn_mfma_f32_16x16x32_bf16(a1, b0, acc[1][0], 0, 0, 0);
    acc[1][1] = __builtin_amdgcn_mfma_f32_16x16x32_bf16(a1, b1, acc[1][1], 0, 0, 0);
  }

  #pragma unroll
  for (int ma = 0; ma < 2; ++ma) {
    #pragma unroll
    for (int nb = 0; nb < 2; ++nb) {
      const int n = n0 + (nh + nb) * 16 + l;
      const float bval = bias[n];
      #pragma unroll
      for (int r = 0; r < 4; ++r) {
        const int m = m0 + (mh + ma) * 16 + quad * 4 + r;
        out[(u32)m * DMODEL + n] = acc[ma][nb][r] + bval;
      }
    }
  }
}

extern "C" void kernel_launch(void* const* d_in, const int* in_sizes, int n_in,
                              void* d_out, int out_size, void* d_ws, size_t ws_size,
                              hipStream_t stream) {
  (void)in_sizes; (void)n_in; (void)out_size; (void)ws_size;
  const float* q  = (const float*)d_in[0];
  const float* k  = (const float*)d_in[1];
  const float* v  = (const float*)d_in[2];
  const float* Wq = (const float*)d_in[3];
  const float* bq = (const float*)d_in[4];
  const float* Wk = (const float*)d_in[5];
  const float* bk = (const float*)d_in[6];
  const float* Wv = (const float*)d_in[7];
  const float* bv = (const float*)d_in[8];
  const float* Wo = (const float*)d_in[9];
  const float* bo = (const float*)d_in[10];

  char* ws = (char*)d_ws;
  u16* Qs   = (u16*)(ws);                 // [bh][s][dk] bf16, pre-scaled 1/8 (16 MB)
  u16* Ks   = (u16*)(ws + 16777216);      // [bh][s][dk]
  u16* Vts  = (u16*)(ws + 33554432);      // [bh][dk][s]  (transposed)
  u16* ctx  = (u16*)(ws + 50331648);      // [b][s][h*dk]  (total ws: 64 MB)

  proj_kernel<<<dim3(128, 16, 3), 256, 0, stream>>>(q, k, v, Wq, Wk, Wv,
                                                    bq, bk, bv, Qs, Ks, Vts);
  attn_kernel<<<dim3(32, 64), 256, 0, stream>>>(Qs, Ks, Vts, ctx);
  oproj_kernel<<<dim3(128, 16), 256, 0, stream>>>(ctx, Wo, bo, (float*)d_out);
}

// Round 11
// 1067.273 us; speedup vs baseline: 1.0756x; 1.0375x over previous
//
#include <hip/hip_runtime.h>
#include <stdint.h>

typedef unsigned short u16;
typedef unsigned int u32;
typedef __attribute__((ext_vector_type(8))) short short8;   // 8 x bf16 (4 VGPRs)
typedef __attribute__((ext_vector_type(4))) float f32x4;

#define DEVI static __device__ __forceinline__

#define S_LEN 2048
#define DMODEL 1024
#define NHEAD 16
#define DK 64
#define NEG_INF (-__builtin_inff())
// u = bitcast((bits>>9)|0x3f800000)-1; boundary 0.9f = 7549747/2^23
// keep:   u > 0.9  <=> bits >= 7549748*512
// dropout keep: u < 0.9  <=> bits <  7549747*512
#define KEEPC 3865470976u
#define DROPC 3865470464u

DEVI u16 f2bf(float f) {
  u32 u = __builtin_bit_cast(u32, f);
  u32 r = u + 0x7fffu + ((u >> 16) & 1u);   // RNE
  return (u16)(r >> 16);
}

DEVI short8 cvt8(float4 a, float4 b) {
  short8 r;
  r[0] = (short)f2bf(a.x); r[1] = (short)f2bf(a.y);
  r[2] = (short)f2bf(a.z); r[3] = (short)f2bf(a.w);
  r[4] = (short)f2bf(b.x); r[5] = (short)f2bf(b.y);
  r[6] = (short)f2bf(b.z); r[7] = (short)f2bf(b.w);
  return r;
}

// JAX threefry2x32 (20 rounds), partitionable draw (default since jax 0.4.36):
// key (0,key), ctr (0,i), bits = o0 ^ o1. Validated bit-exact rounds 2-6, 10.
DEVI u32 tf_bits(u32 key, u32 i) {
  const u32 K2 = key ^ 0x1BD11BDAu;
  u32 x0 = 0u, x1 = i + key;
#define TFR(r) { x0 += x1; x1 = __builtin_rotateleft32(x1, r); x1 ^= x0; }
  TFR(13) TFR(15) TFR(26) TFR(6)  x0 += key; x1 += K2 + 1u;
  TFR(17) TFR(29) TFR(16) TFR(24) x0 += K2;  x1 += 2u;
  TFR(13) TFR(15) TFR(26) TFR(6)  /*x0+=0*/  x1 += key + 3u;
  TFR(17) TFR(29) TFR(16) TFR(24) x0 += key; x1 += K2 + 4u;
  TFR(13) TFR(15) TFR(26) TFR(6)  x0 += K2;  x1 += 5u;
#undef TFR
  return x0 ^ x1;
}

// 16 keep draws for one 16q x 64k lane-tile (branch-free, 16-way ILP).
DEVI u32 keep16(u32 ib) {
  u32 m16 = 0;
  #pragma unroll
  for (int c = 0; c < 4; ++c) {
    #pragma unroll
    for (int r = 0; r < 4; ++r) {
      m16 |= (u32)(tf_bits(42u, ib + (u32)(r * 2048 + c * 16)) >= KEEPC) << (c * 4 + r);
    }
  }
  return m16;
}

// Wave-balanced dropout draws for the kept positions of m16 (validated r3).
// dwp = this wave's 256-slot LDS worklist. Same-wave LDS round trip, no barrier.
// r7-r9 NOTE: the atomicOr-readback/2-barrier/P-alias rework deterministically
// inflated absmax 0.0039->0.028; this r3/r4 form is the validated one.
DEVI u32 drop_balanced(u32 m16, u32 wb, int lane, u16* dwp) {
  const int cnt = __popc(m16);
  int pre = cnt;
  #pragma unroll
  for (int dlt = 1; dlt < 64; dlt <<= 1) {
    int t = __shfl_up(pre, dlt);
    if (lane >= dlt) pre += t;
  }
  const int total = __shfl(pre, 63);   // wave total kept (~102, max ~145)
  pre -= cnt;                          // exclusive prefix = this lane's first slot
  {
    u32 mm = m16; int jj = pre;
    while (mm) {
      const u32 s = (u32)__builtin_ctz(mm); mm &= mm - 1u;
      dwp[jj] = (u16)(((u32)lane << 4) | s);
      ++jj;
    }
  }
  for (int ws2 = lane; ws2 < total; ws2 += 64) {
    const u32 e = (u32)dwp[ws2];
    const u32 oo = e >> 4, ss = e & 15u;
    const u32 ii = wb + ((oo >> 4) * 4u + (ss & 3u)) * 2048u + (oo & 15u) + (ss >> 2) * 16u;
    dwp[ws2] = (u16)(e | ((u32)(tf_bits(7u, ii) < DROPC) << 15));
  }
  u32 d16 = 0;
  {
    u32 mm = m16; int jj = pre;
    while (mm) {
      const u32 s = (u32)__builtin_ctz(mm); mm &= mm - 1u;
      d16 |= (u32)((dwp[jj] >> 15) & 1u) << s;
      ++jj;
    }
  }
  return d16;
}

// ---------------- one-pass fp32 -> bf16 conversion (X x3, W x4) ----------------
// Hoists the f2bf work out of the GEMM k-loops: previously each X element was
// re-converted 16x (once per n-block) as inline VALU. Same f2bf on the same
// values -> downstream MFMA operands are BIT-IDENTICAL to r10.
__global__ __launch_bounds__(256) void cvt_kernel(
    const float* __restrict__ xq, const float* __restrict__ xk, const float* __restrict__ xv,
    const float* __restrict__ wq, const float* __restrict__ wk, const float* __restrict__ wv,
    const float* __restrict__ wo,
    u16* __restrict__ dxq, u16* __restrict__ dxk, u16* __restrict__ dxv,
    u16* __restrict__ dwq, u16* __restrict__ dwk, u16* __restrict__ dwv,
    u16* __restrict__ dwo)
{
  const int z = blockIdx.y;
  const float* s; u16* d; u32 n;
  switch (z) {
    case 0:  s = xq; d = dxq; n = 8388608u; break;
    case 1:  s = xk; d = dxk; n = 8388608u; break;
    case 2:  s = xv; d = dxv; n = 8388608u; break;
    case 3:  s = wq; d = dwq; n = 1048576u; break;
    case 4:  s = wk; d = dwk; n = 1048576u; break;
    case 5:  s = wv; d = dwv; n = 1048576u; break;
    default: s = wo; d = dwo; n = 1048576u; break;
  }
  const u32 i = ((u32)blockIdx.x * 256u + (u32)threadIdx.x) * 8u;
  if (i >= n) return;
  *(short8*)(d + i) = cvt8(*(const float4*)(s + i), *(const float4*)(s + i + 4));
}

// ---------------- QKV projection GEMM (x @ W.T + b), bf16 in, BK=64 ----------------
// 64x64 tile / block, 4 waves (2x2). Staging is now a pure short8 copy (no cvt
// VALU); BK=64 halves the barrier count (32 k-steps -> 16). Per accumulator the
// MFMA k-order is unchanged (monotone) -> bit-exact vs r10.
__global__ __launch_bounds__(256) void proj_kernel(
    const u16* __restrict__ Xq, const u16* __restrict__ Xk, const u16* __restrict__ Xv,
    const u16* __restrict__ Wq, const u16* __restrict__ Wk, const u16* __restrict__ Wv,
    const float* __restrict__ bq, const float* __restrict__ bk, const float* __restrict__ bv,
    u16* __restrict__ Qo, u16* __restrict__ Ko, u16* __restrict__ Vto)
{
  const int z = blockIdx.z;
  const u16* X = (z == 0) ? Xq : (z == 1) ? Xk : Xv;
  const u16* W = (z == 0) ? Wq : (z == 1) ? Wk : Wv;
  const float* bias = (z == 0) ? bq : (z == 1) ? bk : bv;
  const int m0 = blockIdx.x * 64, n0 = blockIdx.y * 64;
  const int tid = threadIdx.x, w = tid >> 6, lane = tid & 63, l = lane & 15, quad = lane >> 4;

  __shared__ __align__(16) u16 lsA[8192], lsB[8192];   // 64 rows x 64 k, two 32-k halves

  const int srow = tid >> 2, skp = tid & 3;
  const int sc = ((srow >> 4) * 64 + skp * 16 + (srow & 15)) * 8;
  const u16* gA = X + (u32)(m0 + srow) * DMODEL + skp * 8;
  const u16* gB = W + (u32)(n0 + srow) * DMODEL + skp * 8;

  f32x4 acc[2][2] = {};
  const int mh = (w >> 1) * 2, nh = (w & 1) * 2;

  for (int k0 = 0; k0 < DMODEL; k0 += 64) {
    short8 a0v = *(const short8*)(gA + k0);
    short8 a1v = *(const short8*)(gA + k0 + 32);
    short8 b0v = *(const short8*)(gB + k0);
    short8 b1v = *(const short8*)(gB + k0 + 32);
    __syncthreads();
    *(short8*)(lsA + sc) = a0v;
    *(short8*)(lsA + 4096 + sc) = a1v;
    *(short8*)(lsB + sc) = b0v;
    *(short8*)(lsB + 4096 + sc) = b1v;
    __syncthreads();
    // k-half 0 (k0..k0+31)
    short8 A00 = *(const short8*)(lsA + ((mh + 0) * 64 + lane) * 8);
    short8 A10 = *(const short8*)(lsA + ((mh + 1) * 64 + lane) * 8);
    short8 B00 = *(const short8*)(lsB + ((nh + 0) * 64 + lane) * 8);
    short8 B10 = *(const short8*)(lsB + ((nh + 1) * 64 + lane) * 8);
    acc[0][0] = __builtin_amdgcn_mfma_f32_16x16x32_bf16(A00, B00, acc[0][0], 0, 0, 0);
    acc[0][1] = __builtin_amdgcn_mfma_f32_16x16x32_bf16(A00, B10, acc[0][1], 0, 0, 0);
    acc[1][0] = __builtin_amdgcn_mfma_f32_16x16x32_bf16(A10, B00, acc[1][0], 0, 0, 0);
    acc[1][1] = __builtin_amdgcn_mfma_f32_16x16x32_bf16(A10, B10, acc[1][1], 0, 0, 0);
    // k-half 1 (k0+32..k0+63)
    short8 A01 = *(const short8*)(lsA + 4096 + ((mh + 0) * 64 + lane) * 8);
    short8 A11 = *(const short8*)(lsA + 4096 + ((mh + 1) * 64 + lane) * 8);
    short8 B01 = *(const short8*)(lsB + 4096 + ((nh + 0) * 64 + lane) * 8);
    short8 B11 = *(const short8*)(lsB + 4096 + ((nh + 1) * 64 + lane) * 8);
    acc[0][0] = __builtin_amdgcn_mfma_f32_16x16x32_bf16(A01, B01, acc[0][0], 0, 0, 0);
    acc[0][1] = __builtin_amdgcn_mfma_f32_16x16x32_bf16(A01, B11, acc[0][1], 0, 0, 0);
    acc[1][0] = __builtin_amdgcn_mfma_f32_16x16x32_bf16(A11, B01, acc[1][0], 0, 0, 0);
    acc[1][1] = __builtin_amdgcn_mfma_f32_16x16x32_bf16(A11, B11, acc[1][1], 0, 0, 0);
  }

  #pragma unroll
  for (int ma = 0; ma < 2; ++ma) {
    #pragma unroll
    for (int nb = 0; nb < 2; ++nb) {
      const int n = n0 + (nh + nb) * 16 + l;
      const float bval = bias[n];
      const int h = n >> 6, d = n & 63;
      #pragma unroll
      for (int r = 0; r < 4; ++r) {
        const int m = m0 + (mh + ma) * 16 + quad * 4 + r;
        float val = acc[ma][nb][r] + bval;
        if (z == 0) val *= 0.125f;              // fold 1/sqrt(dk) into Q
        const int b = m >> 11, s = m & 2047;
        if (z == 0)      Qo [((u32)(b * NHEAD + h) * S_LEN + s) * DK + d] = f2bf(val);
        else if (z == 1) Ko [((u32)(b * NHEAD + h) * S_LEN + s) * DK + d] = f2bf(val);
        else             Vto[((u32)(b * NHEAD + h) * DK + d) * S_LEN + s] = f2bf(val); // V transposed
      }
    }
  }
}

// ---------------- flash attention with INLINE threefry mask + dropout ----------------
// BYTE-IDENTICAL to round-10's passing kernel (831/821 us, absmax 0.0039).
// FROZEN: r7-r9 transport rework deterministically broke absmax; do not touch.
__global__ __launch_bounds__(256) void attn_kernel(
    const u16* __restrict__ Qs, const u16* __restrict__ Ks, const u16* __restrict__ Vts,
    u16* __restrict__ ctx)
{
  const int qb = blockIdx.x, bh = blockIdx.y;
  const int tid = threadIdx.x, w = tid >> 6, lane = tid & 63, l = lane & 15, quad = lane >> 4;

  __shared__ __align__(16) u16 KPf[4096];       // 8 KB: K frags, then per-wave P
  __shared__ __align__(16) u16 Vf[4096];        // 8 KB
  __shared__ __align__(16) u16 dbuf[1024];      // 2 KB: per-wave 256-slot dropout worklist

  // Q A-frags, preloaded (Q pre-scaled by 1/8)
  const int qrow0 = qb * 64 + w * 16;
  const u32 qbase = (u32)(bh * S_LEN + qrow0 + l) * DK + quad * 8;
  const short8 qa0 = *(const short8*)(Qs + qbase);
  const short8 qa1 = *(const short8*)(Qs + qbase + 32);

  // per-lane RNG base: rows start at qrow0+quad*4, col offset l (within tile)
  u32 ibase = ((u32)bh * 2048u + (u32)(qrow0 + quad * 4)) * 2048u + (u32)l;
  // wave-uniform tile base for worker-side index reconstruction
  const u32 wb0 = ((u32)bh * 2048u + (u32)qrow0) * 2048u;
  u16* const dwp = dbuf + w * 256;

  f32x4 o[4] = {};
  float mr[4] = {NEG_INF, NEG_INF, NEG_INF, NEG_INF};
  float lr[4] = {0.f, 0.f, 0.f, 0.f};

  // ---- staging maps: LDS chunk = tid (and tid+256), global derived by inverse map ----
  const int kA  = ((tid >> 6) & 3) * 16 + (tid & 15);
  const int kdp = (tid >> 4) & 3;
  const u32 gk  = (u32)(bh * S_LEN + kA) * DK + kdp * 8;
  const int vd  = ((tid >> 7) & 1) * 16 + (tid & 15);
  const int vsp = ((tid >> 6) & 1) * 4 + ((tid >> 4) & 3);
  const u32 gvA = (u32)(bh * DK + vd) * S_LEN + vsp * 8;
  const u32 gvB = (u32)(bh * DK + vd + 32) * S_LEN + vsp * 8;

  // P staging addresses (swizzled, conflict-free)
  const int hi = l >> 3, j = l & 7;
  const int pxor = ((quad >> 1) << 3) | (hi << 4);
  const int pb = (hi * 128 + quad * 32 + j) ^ pxor;     // r==0 base; bits 3,4 free for r
  const int prd = (lane * 8) ^ (lane & 24);             // swizzled read chunk offset
  u16* const pw = KPf + w * 1024;

  // ---- prologue: loads + RNG for tile 0 ----
  short8 k0v = *(const short8*)(Ks + gk);
  short8 k1v = *(const short8*)(Ks + gk + 32);
  short8 v0v = *(const short8*)(Vts + gvA);
  short8 v1v = *(const short8*)(Vts + gvB);
  u32 m16 = keep16(ibase);
  u32 d16 = drop_balanced(m16, wb0, lane, dwp);
  ibase += 64u;

  for (int kt = 0; kt < 32; ++kt) {
    __syncthreads();                    // prev iter's P/V reads done
    *(short8*)(KPf + tid * 8) = k0v;            // chunk tid        (linear, conflict-free)
    *(short8*)(KPf + 2048 + tid * 8) = k1v;     // chunk tid+256
    *(short8*)(Vf + tid * 8) = v0v;
    *(short8*)(Vf + 2048 + tid * 8) = v1v;
    __syncthreads();

    // issue next tile's loads now: a full iteration of latency cover.
    // kt=31 reads one tile past Ks/Vts ends -- still inside the workspace
    // (never staged/used), so no fault and no clamp needed.
    {
      const u32 ko = (u32)(kt + 1) * 64u;
      k0v = *(const short8*)(Ks + gk + ko * DK);
      k1v = *(const short8*)(Ks + gk + ko * DK + 32);
      v0v = *(const short8*)(Vts + gvA + ko);
      v1v = *(const short8*)(Vts + gvB + ko);
    }

    // S = Q K^T (16q x 64keys per wave), with next tile's keep-draws merged
    // into the same region as VALU filler for the ds_read/MFMA waits.
    f32x4 sc4[4];
    #pragma unroll
    for (int nc = 0; nc < 4; ++nc) {
      short8 kb0 = *(const short8*)(KPf + (nc * 64 + lane) * 8);
      short8 kb1 = *(const short8*)(KPf + ((4 + nc) * 64 + lane) * 8);
      f32x4 zz = {0.f, 0.f, 0.f, 0.f};
      zz = __builtin_amdgcn_mfma_f32_16x16x32_bf16(qa0, kb0, zz, 0, 0, 0);
      sc4[nc] = __builtin_amdgcn_mfma_f32_16x16x32_bf16(qa1, kb1, zz, 0, 0, 0);
    }
    const u32 m16n = keep16(ibase);     // tile kt+1 (kt=31: harmless filler)

    __syncthreads();                    // K fully consumed -> KPf reusable as P

    #pragma unroll
    for (int r = 0; r < 4; ++r) {
      float v0 = ((m16 >> (r + 0))  & 1u) ? sc4[0][r] : NEG_INF;
      float v1 = ((m16 >> (r + 4))  & 1u) ? sc4[1][r] : NEG_INF;
      float v2 = ((m16 >> (r + 8))  & 1u) ? sc4[2][r] : NEG_INF;
      float v3 = ((m16 >> (r + 12)) & 1u) ? sc4[3][r] : NEG_INF;
      float mx = fmaxf(fmaxf(v0, v1), fmaxf(v2, v3));
      mx = fmaxf(mx, __shfl_xor(mx, 1));
      mx = fmaxf(mx, __shfl_xor(mx, 2));
      mx = fmaxf(mx, __shfl_xor(mx, 4));
      mx = fmaxf(mx, __shfl_xor(mx, 8));
      const float mn = fmaxf(mr[r], mx);
      const float mnc = fmaxf(mn, -1e37f);        // clamp: exp(-inf-mnc)=0
      const float alpha = __expf(mr[r] - mnc);    // mr=-inf -> 0 (o,lr are 0)
      mr[r] = mn;
      const float p0 = __expf(v0 - mnc);
      const float p1 = __expf(v1 - mnc);
      const float p2 = __expf(v2 - mnc);
      const float p3 = __expf(v3 - mnc);
      float rs = p0 + p1 + p2 + p3;
      rs += __shfl_xor(rs, 1);
      rs += __shfl_xor(rs, 2);
      rs += __shfl_xor(rs, 4);
      rs += __shfl_xor(rs, 8);
      lr[r] = alpha * lr[r] + rs;
      o[0][r] = o[0][r] * alpha; o[1][r] = o[1][r] * alpha;
      o[2][r] = o[2][r] * alpha; o[3][r] = o[3][r] * alpha;
      // dropout (denominator uses undropped p; numerator uses p*dbit/0.9)
      const float pd0 = ((d16 >> (r + 0))  & 1u) ? p0 * (1.f / 0.9f) : 0.f;
      const float pd1 = ((d16 >> (r + 4))  & 1u) ? p1 * (1.f / 0.9f) : 0.f;
      const float pd2 = ((d16 >> (r + 8))  & 1u) ? p2 * (1.f / 0.9f) : 0.f;
      const float pd3 = ((d16 >> (r + 12)) & 1u) ? p3 * (1.f / 0.9f) : 0.f;
      // write P in A-frag layout (bank-conflict-free via XOR swizzle)
      const int pi = pb ^ (r * 8);
      pw[pi      ] = f2bf(pd0);   // keys  0..15
      pw[pi + 256] = f2bf(pd1);   // keys 16..31
      pw[pi + 512] = f2bf(pd2);   // keys 32..47
      pw[pi + 768] = f2bf(pd3);   // keys 48..63
    }
    // same-wave LDS round-trip: read P as A-frags (swizzled chunk order)
    short8 pa0 = *(const short8*)(pw + prd);
    short8 pa1 = *(const short8*)(pw + 512 + prd);
    #pragma unroll
    for (int nd = 0; nd < 4; ++nd) {
      short8 vb0 = *(const short8*)(Vf + ((nd * 2 + 0) * 64 + lane) * 8);
      short8 vb1 = *(const short8*)(Vf + ((nd * 2 + 1) * 64 + lane) * 8);
      o[nd] = __builtin_amdgcn_mfma_f32_16x16x32_bf16(pa0, vb0, o[nd], 0, 0, 0);
      o[nd] = __builtin_amdgcn_mfma_f32_16x16x32_bf16(pa1, vb1, o[nd], 0, 0, 0);
    }

    // dropout-balance for tile kt+1 (off critical path; dbuf is wave-private)
    u32 d16n = 0;
    if (kt < 31) d16n = drop_balanced(m16n, wb0 + (u32)(kt + 1) * 64u, lane, dwp);
    m16 = m16n; d16 = d16n;
    ibase += 64u;
  }

  const int b = bh >> 4, h = bh & 15;
  #pragma unroll
  for (int r = 0; r < 4; ++r) {
    const float inv = 1.f / lr[r];
    const int qrow = qb * 64 + w * 16 + quad * 4 + r;
    const u32 ob = (u32)(b * S_LEN + qrow) * DMODEL + h * DK;
    ctx[ob + 0  + l] = f2bf(o[0][r] * inv);
    ctx[ob + 16 + l] = f2bf(o[1][r] * inv);
    ctx[ob + 32 + l] = f2bf(o[2][r] * inv);
    ctx[ob + 48 + l] = f2bf(o[3][r] * inv);
  }
}

// ---------------- output projection (ctx @ Wo.T + bo), bf16 A + bf16 B, BK=64 ----------------
__global__ __launch_bounds__(256) void oproj_kernel(
    const u16* __restrict__ X, const u16* __restrict__ W, const float* __restrict__ bias,
    float* __restrict__ out)
{
  const int m0 = blockIdx.x * 64, n0 = blockIdx.y * 64;
  const int tid = threadIdx.x, w = tid >> 6, lane = tid & 63, l = lane & 15, quad = lane >> 4;

  __shared__ __align__(16) u16 lsA[8192], lsB[8192];

  const int srow = tid >> 2, skp = tid & 3;
  const int sc = ((srow >> 4) * 64 + skp * 16 + (srow & 15)) * 8;
  const u16* gA = X + (u32)(m0 + srow) * DMODEL + skp * 8;
  const u16* gB = W + (u32)(n0 + srow) * DMODEL + skp * 8;

  f32x4 acc[2][2] = {};
  const int mh = (w >> 1) * 2, nh = (w & 1) * 2;

  for (int k0 = 0; k0 < DMODEL; k0 += 64) {
    short8 a0v = *(const short8*)(gA + k0);
    short8 a1v = *(const short8*)(gA + k0 + 32);
    short8 b0v = *(const short8*)(gB + k0);
    short8 b1v = *(const short8*)(gB + k0 + 32);
    __syncthreads();
    *(short8*)(lsA + sc) = a0v;
    *(short8*)(lsA + 4096 + sc) = a1v;
    *(short8*)(lsB + sc) = b0v;
    *(short8*)(lsB + 4096 + sc) = b1v;
    __syncthreads();
    short8 A00 = *(const short8*)(lsA + ((mh + 0) * 64 + lane) * 8);
    short8 A10 = *(const short8*)(lsA + ((mh + 1) * 64 + lane) * 8);
    short8 B00 = *(const short8*)(lsB + ((nh + 0) * 64 + lane) * 8);
    short8 B10 = *(const short8*)(lsB + ((nh + 1) * 64 + lane) * 8);
    acc[0][0] = __builtin_amdgcn_mfma_f32_16x16x32_bf16(A00, B00, acc[0][0], 0, 0, 0);
    acc[0][1] = __builtin_amdgcn_mfma_f32_16x16x32_bf16(A00, B10, acc[0][1], 0, 0, 0);
    acc[1][0] = __builtin_amdgcn_mfma_f32_16x16x32_bf16(A10, B00, acc[1][0], 0, 0, 0);
    acc[1][1] = __builtin_amdgcn_mfma_f32_16x16x32_bf16(A10, B10, acc[1][1], 0, 0, 0);
    short8 A01 = *(const short8*)(lsA + 4096 + ((mh + 0) * 64 + lane) * 8);
    short8 A11 = *(const short8*)(lsA + 4096 + ((mh + 1) * 64 + lane) * 8);
    short8 B01 = *(const short8*)(lsB + 4096 + ((nh + 0) * 64 + lane) * 8);
    short8 B11 = *(const short8*)(lsB + 4096 + ((nh + 1) * 64 + lane) * 8);
    acc[0][0] = __builtin_amdgcn_mfma_f32_16x16x32_bf16(A01, B01, acc[0][0], 0, 0, 0);
    acc[0][1] = __builtin_amdgcn_mfma_f32_16x16x32_bf16(A01, B11, acc[0][1], 0, 0, 0);
    acc[1][0] = __builtin_amdgcn_mfma_f32_16x16x32_bf16(A11, B01, acc[1][0], 0, 0, 0);
    acc[1][1] = __builtin_amdgcn_mfma_f32_16x16x32_bf16(A11, B11, acc[1][1], 0, 0, 0);
  }

  #pragma unroll
  for (int ma = 0; ma < 2; ++ma) {
    #pragma unroll
    for (int nb = 0; nb < 2; ++nb) {
      const int n = n0 + (nh + nb) * 16 + l;
      const float bval = bias[n];
      #pragma unroll
      for (int r = 0; r < 4; ++r) {
        const int m = m0 + (mh + ma) * 16 + quad * 4 + r;
        out[(u32)m * DMODEL + n] = acc[ma][nb][r] + bval;
      }
    }
  }
}

extern "C" void kernel_launch(void* const* d_in, const int* in_sizes, int n_in,
                              void* d_out, int out_size, void* d_ws, size_t ws_size,
                              hipStream_t stream) {
  (void)in_sizes; (void)n_in; (void)out_size; (void)ws_size;
  const float* q  = (const float*)d_in[0];
  const float* k  = (const float*)d_in[1];
  const float* v  = (const float*)d_in[2];
  const float* Wq = (const float*)d_in[3];
  const float* bq = (const float*)d_in[4];
  const float* Wk = (const float*)d_in[5];
  const float* bk = (const float*)d_in[6];
  const float* Wv = (const float*)d_in[7];
  const float* bv = (const float*)d_in[8];
  const float* Wo = (const float*)d_in[9];
  const float* bo = (const float*)d_in[10];

  // Workspace layout (120 MiB used; ws_size >= 128 MiB proven on this harness
  // by round-6's maskgen branch executing):
  char* ws = (char*)d_ws;
  u16* Qs   = (u16*)(ws);                   // [bh][s][dk] bf16, pre-scaled 1/8 (16 MB)
  u16* Ks   = (u16*)(ws + 16777216);        // [bh][s][dk]
  u16* Vts  = (u16*)(ws + 33554432);        // [bh][dk][s]  (transposed)
  u16* ctx  = (u16*)(ws + 50331648);        // [b][s][h*dk]
  u16* Xqb  = (u16*)(ws + 67108864);        // bf16 copies of X (16 MB each)
  u16* Xkb  = (u16*)(ws + 83886080);
  u16* Xvb  = (u16*)(ws + 100663296);
  u16* Wqb  = (u16*)(ws + 117440512);       // bf16 copies of W (2 MB each)
  u16* Wkb  = (u16*)(ws + 119537664);
  u16* Wvb  = (u16*)(ws + 121634816);
  u16* Wob  = (u16*)(ws + 123731968);       // end: 125829120 (120 MB)

  cvt_kernel<<<dim3(4096, 7), 256, 0, stream>>>(q, k, v, Wq, Wk, Wv, Wo,
                                                Xqb, Xkb, Xvb, Wqb, Wkb, Wvb, Wob);
  proj_kernel<<<dim3(128, 16, 3), 256, 0, stream>>>(Xqb, Xkb, Xvb, Wqb, Wkb, Wvb,
                                                    bq, bk, bv, Qs, Ks, Vts);
  attn_kernel<<<dim3(32, 64), 256, 0, stream>>>(Qs, Ks, Vts, ctx);
  oproj_kernel<<<dim3(128, 16), 256, 0, stream>>>(ctx, Wob, bo, (float*)d_out);
}

// Round 12
// 1049.968 us; speedup vs baseline: 1.0933x; 1.0165x over previous
//
#include <hip/hip_runtime.h>
#include <stdint.h>

typedef unsigned short u16;
typedef unsigned int u32;
typedef __attribute__((ext_vector_type(8))) short short8;   // 8 x bf16 (4 VGPRs)
typedef __attribute__((ext_vector_type(4))) float f32x4;

#define DEVI static __device__ __forceinline__

#define S_LEN 2048
#define DMODEL 1024
#define NHEAD 16
#define DK 64
#define NEG_INF (-__builtin_inff())
// u = bitcast((bits>>9)|0x3f800000)-1; boundary 0.9f = 7549747/2^23
// keep:   u > 0.9  <=> bits >= 7549748*512
// dropout keep: u < 0.9  <=> bits <  7549747*512
#define KEEPC 3865470976u
#define DROPC 3865470464u

DEVI u16 f2bf(float f) {
  u32 u = __builtin_bit_cast(u32, f);
  u32 r = u + 0x7fffu + ((u >> 16) & 1u);   // RNE
  return (u16)(r >> 16);
}

DEVI short8 cvt8(float4 a, float4 b) {
  short8 r;
  r[0] = (short)f2bf(a.x); r[1] = (short)f2bf(a.y);
  r[2] = (short)f2bf(a.z); r[3] = (short)f2bf(a.w);
  r[4] = (short)f2bf(b.x); r[5] = (short)f2bf(b.y);
  r[6] = (short)f2bf(b.z); r[7] = (short)f2bf(b.w);
  return r;
}

// JAX threefry2x32 (20 rounds), partitionable draw (default since jax 0.4.36):
// key (0,key), ctr (0,i), bits = o0 ^ o1. Validated bit-exact rounds 2-6, 10-11.
DEVI u32 tf_bits(u32 key, u32 i) {
  const u32 K2 = key ^ 0x1BD11BDAu;
  u32 x0 = 0u, x1 = i + key;
#define TFR(r) { x0 += x1; x1 = __builtin_rotateleft32(x1, r); x1 ^= x0; }
  TFR(13) TFR(15) TFR(26) TFR(6)  x0 += key; x1 += K2 + 1u;
  TFR(17) TFR(29) TFR(16) TFR(24) x0 += K2;  x1 += 2u;
  TFR(13) TFR(15) TFR(26) TFR(6)  /*x0+=0*/  x1 += key + 3u;
  TFR(17) TFR(29) TFR(16) TFR(24) x0 += key; x1 += K2 + 4u;
  TFR(13) TFR(15) TFR(26) TFR(6)  x0 += K2;  x1 += 5u;
#undef TFR
  return x0 ^ x1;
}

// 16 keep draws for one 16q x 64k lane-tile (branch-free, 16-way ILP).
DEVI u32 keep16(u32 ib) {
  u32 m16 = 0;
  #pragma unroll
  for (int c = 0; c < 4; ++c) {
    #pragma unroll
    for (int r = 0; r < 4; ++r) {
      m16 |= (u32)(tf_bits(42u, ib + (u32)(r * 2048 + c * 16)) >= KEEPC) << (c * 4 + r);
    }
  }
  return m16;
}

// Wave-balanced dropout draws for the kept positions of m16 (validated r3).
// dwp = this wave's 256-slot LDS worklist. Same-wave LDS round trip, no barrier.
// r7-r9 NOTE: the atomicOr-readback/2-barrier/P-alias rework deterministically
// inflated absmax 0.0039->0.028; this r3/r4 form is the validated one.
DEVI u32 drop_balanced(u32 m16, u32 wb, int lane, u16* dwp) {
  const int cnt = __popc(m16);
  int pre = cnt;
  #pragma unroll
  for (int dlt = 1; dlt < 64; dlt <<= 1) {
    int t = __shfl_up(pre, dlt);
    if (lane >= dlt) pre += t;
  }
  const int total = __shfl(pre, 63);   // wave total kept (~102, max ~145)
  pre -= cnt;                          // exclusive prefix = this lane's first slot
  {
    u32 mm = m16; int jj = pre;
    while (mm) {
      const u32 s = (u32)__builtin_ctz(mm); mm &= mm - 1u;
      dwp[jj] = (u16)(((u32)lane << 4) | s);
      ++jj;
    }
  }
  for (int ws2 = lane; ws2 < total; ws2 += 64) {
    const u32 e = (u32)dwp[ws2];
    const u32 oo = e >> 4, ss = e & 15u;
    const u32 ii = wb + ((oo >> 4) * 4u + (ss & 3u)) * 2048u + (oo & 15u) + (ss >> 2) * 16u;
    dwp[ws2] = (u16)(e | ((u32)(tf_bits(7u, ii) < DROPC) << 15));
  }
  u32 d16 = 0;
  {
    u32 mm = m16; int jj = pre;
    while (mm) {
      const u32 s = (u32)__builtin_ctz(mm); mm &= mm - 1u;
      d16 |= (u32)((dwp[jj] >> 15) & 1u) << s;
      ++jj;
    }
  }
  return d16;
}

// ---------------- one-pass fp32 -> bf16 conversion (X x3, W x4) ----------------
// Same f2bf on the same values as inline conversion -> downstream MFMA operands
// BIT-IDENTICAL. Validated r11.
__global__ __launch_bounds__(256) void cvt_kernel(
    const float* __restrict__ xq, const float* __restrict__ xk, const float* __restrict__ xv,
    const float* __restrict__ wq, const float* __restrict__ wk, const float* __restrict__ wv,
    const float* __restrict__ wo,
    u16* __restrict__ dxq, u16* __restrict__ dxk, u16* __restrict__ dxv,
    u16* __restrict__ dwq, u16* __restrict__ dwk, u16* __restrict__ dwv,
    u16* __restrict__ dwo)
{
  const int z = blockIdx.y;
  const float* s; u16* d; u32 n;
  switch (z) {
    case 0:  s = xq; d = dxq; n = 8388608u; break;
    case 1:  s = xk; d = dxk; n = 8388608u; break;
    case 2:  s = xv; d = dxv; n = 8388608u; break;
    case 3:  s = wq; d = dwq; n = 1048576u; break;
    case 4:  s = wk; d = dwk; n = 1048576u; break;
    case 5:  s = wv; d = dwv; n = 1048576u; break;
    default: s = wo; d = dwo; n = 1048576u; break;
  }
  const u32 i = ((u32)blockIdx.x * 256u + (u32)threadIdx.x) * 8u;
  if (i >= n) return;
  *(short8*)(d + i) = cvt8(*(const float4*)(s + i), *(const float4*)(s + i + 4));
}

// ---------------- QKV projection GEMM (x @ W.T + b), bf16 in, 128x128 tile ----------------
// r12: 128x128 tile / block, 4 waves (2x2), each wave 64x64 via 4x4 C-frags.
// MFMA:ds_read ratio 2:1 (vs 1:1 at 64^2); 16 k-steps, 2 barriers each.
// Per-acc k-order is the same monotone (k0 asc, half0 then half1) with the same
// MFMA instruction -> output BIT-IDENTICAL to r11/r10.
// LDS chunk layout per 32-k half: chunk c = rowblk*64 + kslot*16 + (row&15),
// chunk c holds row (c>>6)*16+(c&15), k bytes [kslot*16, +16). Staging chunk =
// tid (+256); frag read chunk = rowblk*64 + lane (ds_read_b128, conflict-free).
__global__ __launch_bounds__(256) void proj_kernel(
    const u16* __restrict__ Xq, const u16* __restrict__ Xk, const u16* __restrict__ Xv,
    const u16* __restrict__ Wq, const u16* __restrict__ Wk, const u16* __restrict__ Wv,
    const float* __restrict__ bq, const float* __restrict__ bk, const float* __restrict__ bv,
    u16* __restrict__ Qo, u16* __restrict__ Ko, u16* __restrict__ Vto)
{
  const int z = blockIdx.z;
  const u16* X = (z == 0) ? Xq : (z == 1) ? Xk : Xv;
  const u16* W = (z == 0) ? Wq : (z == 1) ? Wk : Wv;
  const float* bias = (z == 0) ? bq : (z == 1) ? bk : bv;
  const int m0 = blockIdx.x * 128, n0 = blockIdx.y * 128;
  const int tid = threadIdx.x, w = tid >> 6, lane = tid & 63, l = lane & 15, quad = lane >> 4;

  __shared__ __align__(16) u16 lsA[8192], lsB[8192];   // 128 rows x 64 k (two 32-k halves)

  // staging inverse map: chunk tid -> row (tid>>6)*16+(tid&15), kslot (tid>>4)&3
  const int srow = (tid >> 6) * 16 + (tid & 15);
  const int skp  = (tid >> 4) & 3;
  const u16* gA = X + (u32)(m0 + srow) * DMODEL + skp * 8;
  const u16* gB = W + (u32)(n0 + srow) * DMODEL + skp * 8;
  const int sc = tid * 8;

  f32x4 acc[4][4] = {};
  const int rb = (w >> 1) * 4, cb = (w & 1) * 4;   // wave's rowblk/colblk base

  for (int k0 = 0; k0 < DMODEL; k0 += 64) {
    short8 a0 = *(const short8*)(gA + k0);                 // half0, rows 0-63 part
    short8 a1 = *(const short8*)(gA + k0 + 64 * DMODEL);   // half0, rows 64-127
    short8 a2 = *(const short8*)(gA + k0 + 32);            // half1
    short8 a3 = *(const short8*)(gA + k0 + 64 * DMODEL + 32);
    short8 b0 = *(const short8*)(gB + k0);
    short8 b1 = *(const short8*)(gB + k0 + 64 * DMODEL);
    short8 b2 = *(const short8*)(gB + k0 + 32);
    short8 b3 = *(const short8*)(gB + k0 + 64 * DMODEL + 32);
    __syncthreads();
    *(short8*)(lsA + sc)        = a0;    // half0 chunk tid
    *(short8*)(lsA + 2048 + sc) = a1;    // half0 chunk tid+256
    *(short8*)(lsA + 4096 + sc) = a2;    // half1 chunk tid
    *(short8*)(lsA + 6144 + sc) = a3;    // half1 chunk tid+256
    *(short8*)(lsB + sc)        = b0;
    *(short8*)(lsB + 2048 + sc) = b1;
    *(short8*)(lsB + 4096 + sc) = b2;
    *(short8*)(lsB + 6144 + sc) = b3;
    __syncthreads();
    #pragma unroll
    for (int h = 0; h < 2; ++h) {
      short8 af[4], bf[4];
      #pragma unroll
      for (int i = 0; i < 4; ++i) {
        af[i] = *(const short8*)(lsA + h * 4096 + ((rb + i) * 64 + lane) * 8);
        bf[i] = *(const short8*)(lsB + h * 4096 + ((cb + i) * 64 + lane) * 8);
      }
      #pragma unroll
      for (int ma = 0; ma < 4; ++ma) {
        #pragma unroll
        for (int nb = 0; nb < 4; ++nb) {
          acc[ma][nb] = __builtin_amdgcn_mfma_f32_16x16x32_bf16(af[ma], bf[nb], acc[ma][nb], 0, 0, 0);
        }
      }
    }
  }

  #pragma unroll
  for (int ma = 0; ma < 4; ++ma) {
    #pragma unroll
    for (int nb = 0; nb < 4; ++nb) {
      const int n = n0 + (cb + nb) * 16 + l;
      const float bval = bias[n];
      const int h = n >> 6, d = n & 63;
      #pragma unroll
      for (int r = 0; r < 4; ++r) {
        const int m = m0 + (rb + ma) * 16 + quad * 4 + r;
        float val = acc[ma][nb][r] + bval;
        if (z == 0) val *= 0.125f;              // fold 1/sqrt(dk) into Q
        const int b = m >> 11, s = m & 2047;
        if (z == 0)      Qo [((u32)(b * NHEAD + h) * S_LEN + s) * DK + d] = f2bf(val);
        else if (z == 1) Ko [((u32)(b * NHEAD + h) * S_LEN + s) * DK + d] = f2bf(val);
        else             Vto[((u32)(b * NHEAD + h) * DK + d) * S_LEN + s] = f2bf(val); // V transposed
      }
    }
  }
}

// ---------------- flash attention with INLINE threefry mask + dropout ----------------
// BYTE-IDENTICAL to round-10/11's passing kernel (821-836 us, absmax 0.0039).
// FROZEN: r7-r9 transport rework deterministically broke absmax; do not touch.
__global__ __launch_bounds__(256) void attn_kernel(
    const u16* __restrict__ Qs, const u16* __restrict__ Ks, const u16* __restrict__ Vts,
    u16* __restrict__ ctx)
{
  const int qb = blockIdx.x, bh = blockIdx.y;
  const int tid = threadIdx.x, w = tid >> 6, lane = tid & 63, l = lane & 15, quad = lane >> 4;

  __shared__ __align__(16) u16 KPf[4096];       // 8 KB: K frags, then per-wave P
  __shared__ __align__(16) u16 Vf[4096];        // 8 KB
  __shared__ __align__(16) u16 dbuf[1024];      // 2 KB: per-wave 256-slot dropout worklist

  // Q A-frags, preloaded (Q pre-scaled by 1/8)
  const int qrow0 = qb * 64 + w * 16;
  const u32 qbase = (u32)(bh * S_LEN + qrow0 + l) * DK + quad * 8;
  const short8 qa0 = *(const short8*)(Qs + qbase);
  const short8 qa1 = *(const short8*)(Qs + qbase + 32);

  // per-lane RNG base: rows start at qrow0+quad*4, col offset l (within tile)
  u32 ibase = ((u32)bh * 2048u + (u32)(qrow0 + quad * 4)) * 2048u + (u32)l;
  // wave-uniform tile base for worker-side index reconstruction
  const u32 wb0 = ((u32)bh * 2048u + (u32)qrow0) * 2048u;
  u16* const dwp = dbuf + w * 256;

  f32x4 o[4] = {};
  float mr[4] = {NEG_INF, NEG_INF, NEG_INF, NEG_INF};
  float lr[4] = {0.f, 0.f, 0.f, 0.f};

  // ---- staging maps: LDS chunk = tid (and tid+256), global derived by inverse map ----
  const int kA  = ((tid >> 6) & 3) * 16 + (tid & 15);
  const int kdp = (tid >> 4) & 3;
  const u32 gk  = (u32)(bh * S_LEN + kA) * DK + kdp * 8;
  const int vd  = ((tid >> 7) & 1) * 16 + (tid & 15);
  const int vsp = ((tid >> 6) & 1) * 4 + ((tid >> 4) & 3);
  const u32 gvA = (u32)(bh * DK + vd) * S_LEN + vsp * 8;
  const u32 gvB = (u32)(bh * DK + vd + 32) * S_LEN + vsp * 8;

  // P staging addresses (swizzled, conflict-free)
  const int hi = l >> 3, j = l & 7;
  const int pxor = ((quad >> 1) << 3) | (hi << 4);
  const int pb = (hi * 128 + quad * 32 + j) ^ pxor;     // r==0 base; bits 3,4 free for r
  const int prd = (lane * 8) ^ (lane & 24);             // swizzled read chunk offset
  u16* const pw = KPf + w * 1024;

  // ---- prologue: loads + RNG for tile 0 ----
  short8 k0v = *(const short8*)(Ks + gk);
  short8 k1v = *(const short8*)(Ks + gk + 32);
  short8 v0v = *(const short8*)(Vts + gvA);
  short8 v1v = *(const short8*)(Vts + gvB);
  u32 m16 = keep16(ibase);
  u32 d16 = drop_balanced(m16, wb0, lane, dwp);
  ibase += 64u;

  for (int kt = 0; kt < 32; ++kt) {
    __syncthreads();                    // prev iter's P/V reads done
    *(short8*)(KPf + tid * 8) = k0v;            // chunk tid        (linear, conflict-free)
    *(short8*)(KPf + 2048 + tid * 8) = k1v;     // chunk tid+256
    *(short8*)(Vf + tid * 8) = v0v;
    *(short8*)(Vf + 2048 + tid * 8) = v1v;
    __syncthreads();

    // issue next tile's loads now: a full iteration of latency cover.
    // kt=31 reads one tile past Ks/Vts ends -- still inside the workspace
    // (never staged/used), so no fault and no clamp needed.
    {
      const u32 ko = (u32)(kt + 1) * 64u;
      k0v = *(const short8*)(Ks + gk + ko * DK);
      k1v = *(const short8*)(Ks + gk + ko * DK + 32);
      v0v = *(const short8*)(Vts + gvA + ko);
      v1v = *(const short8*)(Vts + gvB + ko);
    }

    // S = Q K^T (16q x 64keys per wave), with next tile's keep-draws merged
    // into the same region as VALU filler for the ds_read/MFMA waits.
    f32x4 sc4[4];
    #pragma unroll
    for (int nc = 0; nc < 4; ++nc) {
      short8 kb0 = *(const short8*)(KPf + (nc * 64 + lane) * 8);
      short8 kb1 = *(const short8*)(KPf + ((4 + nc) * 64 + lane) * 8);
      f32x4 zz = {0.f, 0.f, 0.f, 0.f};
      zz = __builtin_amdgcn_mfma_f32_16x16x32_bf16(qa0, kb0, zz, 0, 0, 0);
      sc4[nc] = __builtin_amdgcn_mfma_f32_16x16x32_bf16(qa1, kb1, zz, 0, 0, 0);
    }
    const u32 m16n = keep16(ibase);     // tile kt+1 (kt=31: harmless filler)

    __syncthreads();                    // K fully consumed -> KPf reusable as P

    #pragma unroll
    for (int r = 0; r < 4; ++r) {
      float v0 = ((m16 >> (r + 0))  & 1u) ? sc4[0][r] : NEG_INF;
      float v1 = ((m16 >> (r + 4))  & 1u) ? sc4[1][r] : NEG_INF;
      float v2 = ((m16 >> (r + 8))  & 1u) ? sc4[2][r] : NEG_INF;
      float v3 = ((m16 >> (r + 12)) & 1u) ? sc4[3][r] : NEG_INF;
      float mx = fmaxf(fmaxf(v0, v1), fmaxf(v2, v3));
      mx = fmaxf(mx, __shfl_xor(mx, 1));
      mx = fmaxf(mx, __shfl_xor(mx, 2));
      mx = fmaxf(mx, __shfl_xor(mx, 4));
      mx = fmaxf(mx, __shfl_xor(mx, 8));
      const float mn = fmaxf(mr[r], mx);
      const float mnc = fmaxf(mn, -1e37f);        // clamp: exp(-inf-mnc)=0
      const float alpha = __expf(mr[r] - mnc);    // mr=-inf -> 0 (o,lr are 0)
      mr[r] = mn;
      const float p0 = __expf(v0 - mnc);
      const float p1 = __expf(v1 - mnc);
      const float p2 = __expf(v2 - mnc);
      const float p3 = __expf(v3 - mnc);
      float rs = p0 + p1 + p2 + p3;
      rs += __shfl_xor(rs, 1);
      rs += __shfl_xor(rs, 2);
      rs += __shfl_xor(rs, 4);
      rs += __shfl_xor(rs, 8);
      lr[r] = alpha * lr[r] + rs;
      o[0][r] = o[0][r] * alpha; o[1][r] = o[1][r] * alpha;
      o[2][r] = o[2][r] * alpha; o[3][r] = o[3][r] * alpha;
      // dropout (denominator uses undropped p; numerator uses p*dbit/0.9)
      const float pd0 = ((d16 >> (r + 0))  & 1u) ? p0 * (1.f / 0.9f) : 0.f;
      const float pd1 = ((d16 >> (r + 4))  & 1u) ? p1 * (1.f / 0.9f) : 0.f;
      const float pd2 = ((d16 >> (r + 8))  & 1u) ? p2 * (1.f / 0.9f) : 0.f;
      const float pd3 = ((d16 >> (r + 12)) & 1u) ? p3 * (1.f / 0.9f) : 0.f;
      // write P in A-frag layout (bank-conflict-free via XOR swizzle)
      const int pi = pb ^ (r * 8);
      pw[pi      ] = f2bf(pd0);   // keys  0..15
      pw[pi + 256] = f2bf(pd1);   // keys 16..31
      pw[pi + 512] = f2bf(pd2);   // keys 32..47
      pw[pi + 768] = f2bf(pd3);   // keys 48..63
    }
    // same-wave LDS round-trip: read P as A-frags (swizzled chunk order)
    short8 pa0 = *(const short8*)(pw + prd);
    short8 pa1 = *(const short8*)(pw + 512 + prd);
    #pragma unroll
    for (int nd = 0; nd < 4; ++nd) {
      short8 vb0 = *(const short8*)(Vf + ((nd * 2 + 0) * 64 + lane) * 8);
      short8 vb1 = *(const short8*)(Vf + ((nd * 2 + 1) * 64 + lane) * 8);
      o[nd] = __builtin_amdgcn_mfma_f32_16x16x32_bf16(pa0, vb0, o[nd], 0, 0, 0);
      o[nd] = __builtin_amdgcn_mfma_f32_16x16x32_bf16(pa1, vb1, o[nd], 0, 0, 0);
    }

    // dropout-balance for tile kt+1 (off critical path; dbuf is wave-private)
    u32 d16n = 0;
    if (kt < 31) d16n = drop_balanced(m16n, wb0 + (u32)(kt + 1) * 64u, lane, dwp);
    m16 = m16n; d16 = d16n;
    ibase += 64u;
  }

  const int b = bh >> 4, h = bh & 15;
  #pragma unroll
  for (int r = 0; r < 4; ++r) {
    const float inv = 1.f / lr[r];
    const int qrow = qb * 64 + w * 16 + quad * 4 + r;
    const u32 ob = (u32)(b * S_LEN + qrow) * DMODEL + h * DK;
    ctx[ob + 0  + l] = f2bf(o[0][r] * inv);
    ctx[ob + 16 + l] = f2bf(o[1][r] * inv);
    ctx[ob + 32 + l] = f2bf(o[2][r] * inv);
    ctx[ob + 48 + l] = f2bf(o[3][r] * inv);
  }
}

// ---------------- output projection (ctx @ Wo.T + bo), bf16 in, 128x128 tile ----------------
__global__ __launch_bounds__(256) void oproj_kernel(
    const u16* __restrict__ X, const u16* __restrict__ W, const float* __restrict__ bias,
    float* __restrict__ out)
{
  const int m0 = blockIdx.x * 128, n0 = blockIdx.y * 128;
  const int tid = threadIdx.x, w = tid >> 6, lane = tid & 63, l = lane & 15, quad = lane >> 4;

  __shared__ __align__(16) u16 lsA[8192], lsB[8192];

  const int srow = (tid >> 6) * 16 + (tid & 15);
  const int skp  = (tid >> 4) & 3;
  const u16* gA = X + (u32)(m0 + srow) * DMODEL + skp * 8;
  const u16* gB = W + (u32)(n0 + srow) * DMODEL + skp * 8;
  const int sc = tid * 8;

  f32x4 acc[4][4] = {};
  const int rb = (w >> 1) * 4, cb = (w & 1) * 4;

  for (int k0 = 0; k0 < DMODEL; k0 += 64) {
    short8 a0 = *(const short8*)(gA + k0);
    short8 a1 = *(const short8*)(gA + k0 + 64 * DMODEL);
    short8 a2 = *(const short8*)(gA + k0 + 32);
    short8 a3 = *(const short8*)(gA + k0 + 64 * DMODEL + 32);
    short8 b0 = *(const short8*)(gB + k0);
    short8 b1 = *(const short8*)(gB + k0 + 64 * DMODEL);
    short8 b2 = *(const short8*)(gB + k0 + 32);
    short8 b3 = *(const short8*)(gB + k0 + 64 * DMODEL + 32);
    __syncthreads();
    *(short8*)(lsA + sc)        = a0;
    *(short8*)(lsA + 2048 + sc) = a1;
    *(short8*)(lsA + 4096 + sc) = a2;
    *(short8*)(lsA + 6144 + sc) = a3;
    *(short8*)(lsB + sc)        = b0;
    *(short8*)(lsB + 2048 + sc) = b1;
    *(short8*)(lsB + 4096 + sc) = b2;
    *(short8*)(lsB + 6144 + sc) = b3;
    __syncthreads();
    #pragma unroll
    for (int h = 0; h < 2; ++h) {
      short8 af[4], bf[4];
      #pragma unroll
      for (int i = 0; i < 4; ++i) {
        af[i] = *(const short8*)(lsA + h * 4096 + ((rb + i) * 64 + lane) * 8);
        bf[i] = *(const short8*)(lsB + h * 4096 + ((cb + i) * 64 + lane) * 8);
      }
      #pragma unroll
      for (int ma = 0; ma < 4; ++ma) {
        #pragma unroll
        for (int nb = 0; nb < 4; ++nb) {
          acc[ma][nb] = __builtin_amdgcn_mfma_f32_16x16x32_bf16(af[ma], bf[nb], acc[ma][nb], 0, 0, 0);
        }
      }
    }
  }

  #pragma unroll
  for (int ma = 0; ma < 4; ++ma) {
    #pragma unroll
    for (int nb = 0; nb < 4; ++nb) {
      const int n = n0 + (cb + nb) * 16 + l;
      const float bval = bias[n];
      #pragma unroll
      for (int r = 0; r < 4; ++r) {
        const int m = m0 + (rb + ma) * 16 + quad * 4 + r;
        out[(u32)m * DMODEL + n] = acc[ma][nb][r] + bval;
      }
    }
  }
}

extern "C" void kernel_launch(void* const* d_in, const int* in_sizes, int n_in,
                              void* d_out, int out_size, void* d_ws, size_t ws_size,
                              hipStream_t stream) {
  (void)in_sizes; (void)n_in; (void)out_size; (void)ws_size;
  const float* q  = (const float*)d_in[0];
  const float* k  = (const float*)d_in[1];
  const float* v  = (const float*)d_in[2];
  const float* Wq = (const float*)d_in[3];
  const float* bq = (const float*)d_in[4];
  const float* Wk = (const float*)d_in[5];
  const float* bk = (const float*)d_in[6];
  const float* Wv = (const float*)d_in[7];
  const float* bv = (const float*)d_in[8];
  const float* Wo = (const float*)d_in[9];
  const float* bo = (const float*)d_in[10];

  // Workspace layout (120 MiB used; ws_size >= 128 MiB proven on this harness
  // by round-6's maskgen branch executing):
  char* ws = (char*)d_ws;
  u16* Qs   = (u16*)(ws);                   // [bh][s][dk] bf16, pre-scaled 1/8 (16 MB)
  u16* Ks   = (u16*)(ws + 16777216);        // [bh][s][dk]
  u16* Vts  = (u16*)(ws + 33554432);        // [bh][dk][s]  (transposed)
  u16* ctx  = (u16*)(ws + 50331648);        // [b][s][h*dk]
  u16* Xqb  = (u16*)(ws + 67108864);        // bf16 copies of X (16 MB each)
  u16* Xkb  = (u16*)(ws + 83886080);
  u16* Xvb  = (u16*)(ws + 100663296);
  u16* Wqb  = (u16*)(ws + 117440512);       // bf16 copies of W (2 MB each)
  u16* Wkb  = (u16*)(ws + 119537664);
  u16* Wvb  = (u16*)(ws + 121634816);
  u16* Wob  = (u16*)(ws + 123731968);       // end: 125829120 (120 MB)

  cvt_kernel<<<dim3(4096, 7), 256, 0, stream>>>(q, k, v, Wq, Wk, Wv, Wo,
                                                Xqb, Xkb, Xvb, Wqb, Wkb, Wvb, Wob);
  proj_kernel<<<dim3(64, 8, 3), 256, 0, stream>>>(Xqb, Xkb, Xvb, Wqb, Wkb, Wvb,
                                                  bq, bk, bv, Qs, Ks, Vts);
  attn_kernel<<<dim3(32, 64), 256, 0, stream>>>(Qs, Ks, Vts, ctx);
  oproj_kernel<<<dim3(64, 8), 256, 0, stream>>>(ctx, Wob, bo, (float*)d_out);
}